// Round 10
// baseline (195.247 us; speedup 1.0000x reference)
//
// v8.0 — proj overhauled with r9 recipe: dbuf LDS + T14 reg-prefetch + 1 barrier/iter
//        + cvt_pk packing. Attention (8-wave parity-split, r9 win) unchanged.
#include <hip/hip_runtime.h>
#include <stdint.h>

#define B_ 8
#define S_ 4096
#define E_ 1024
#define H_ 128
#define M_ (B_*S_)

typedef __attribute__((ext_vector_type(8))) short short8;
typedef __attribute__((ext_vector_type(4))) float f32x4;
typedef __attribute__((ext_vector_type(16))) float f32x16;

static constexpr float QSCALE = 0.08838834764831845f; // 1/sqrt(128)

__device__ __forceinline__ unsigned short f2bf(float f) {
    uint32_t u = __float_as_uint(f);
    u += 0x7fffu + ((u >> 16) & 1u);
    return (unsigned short)(u >> 16);
}

__device__ __forceinline__ uint32_t cvt_pk_bf16(float a, float b) {
    uint32_t r;
    asm("v_cvt_pk_bf16_f32 %0, %1, %2" : "=v"(r) : "v"(a), "v"(b));
    return r;
}

// ---------------- W transpose + bf16 convert: Wt[3][128][1024] ----------------
__global__ __launch_bounds__(256)
void prep_w_kernel(const float* __restrict__ Wq, const float* __restrict__ Wk,
                   const float* __restrict__ Wv, unsigned short* __restrict__ Wt)
{
    int id = blockIdx.x*256 + threadIdx.x;
    int which = id >> 14;
    int rem = id & 16383;
    int h = rem >> 7, kc = rem & 127;
    const float* __restrict__ W = (which==0)?Wq:((which==1)?Wk:Wv);
    const float scale = (which==0)? QSCALE : 1.0f;
    uint32_t u[4];
    #pragma unroll
    for (int p=0;p<4;++p) {
        unsigned short a = f2bf(W[(size_t)(kc*8 + 2*p  )*H_ + h] * scale);
        unsigned short b = f2bf(W[(size_t)(kc*8 + 2*p+1)*H_ + h] * scale);
        u[p] = (uint32_t)a | ((uint32_t)b << 16);
    }
    uint4 v; v.x=u[0]; v.y=u[1]; v.z=u[2]; v.w=u[3];
    *(uint4*)(Wt + (size_t)(which*H_ + h)*E_ + kc*8) = v;
}

// ---------------- QKV projection v2: dbuf + reg-prefetch + 1 barrier/iter ----------------
// grid (M_/128, 3), block 256 (4 waves). BM=128, BN=128, BK=64.
__global__ __launch_bounds__(256)
void proj_kernel(const float* __restrict__ x, const unsigned short* __restrict__ Wt,
                 unsigned short* __restrict__ Qg, unsigned short* __restrict__ Kg,
                 unsigned short* __restrict__ Vtg)
{
    const int t = threadIdx.x;
    const int w = t >> 6, l = t & 63;
    const int grp = l >> 4, li = l & 15;
    const int rb = blockIdx.x;
    const int which = blockIdx.y;
    const int row0 = rb * 128;

    __shared__ __align__(128) unsigned char smem[65536];  // 2 x (sX 16K + sW 16K); epi reuses
    unsigned char* epi = smem;

    const unsigned char* Wslice = (const unsigned char*)(Wt + (size_t)which*H_*E_);

    f32x4 acc[2][8];
    const f32x4 zz = {0.f,0.f,0.f,0.f};
    #pragma unroll
    for (int mt=0;mt<2;++mt)
        #pragma unroll
        for (int nt=0;nt<8;++nt) acc[mt][nt] = zz;

    // per-thread staging geometry (k-invariant)
    const int xrow = t >> 4, xc4 = t & 15;               // x: rows t>>4 + 16*i
    const int wh   = t >> 3, wcb = (t & 7) * 16;         // W: h rows t>>3 + 32*i

    float4 px[8];
    uint4  pw[4];

    // prologue: load + stage k0=0 into buffer 0
    #pragma unroll
    for (int i=0;i<8;++i)
        px[i] = *(const float4*)(x + (size_t)(row0 + xrow + 16*i)*E_ + 0 + xc4*4);
    #pragma unroll
    for (int i=0;i<4;++i)
        pw[i] = *(const uint4*)(Wslice + (size_t)(wh + 32*i)*2048 + 0 + wcb);
    #pragma unroll
    for (int i=0;i<8;++i) {
        int row = xrow + 16*i;
        uint2 pv;
        pv.x = cvt_pk_bf16(px[i].x, px[i].y);
        pv.y = cvt_pk_bf16(px[i].z, px[i].w);
        *(uint2*)(smem + row*128 + ((xc4*8) ^ ((row&7)<<4))) = pv;
    }
    #pragma unroll
    for (int i=0;i<4;++i) {
        int h = wh + 32*i;
        *(uint4*)(smem + 16384 + h*128 + (wcb ^ ((h&7)<<4))) = pw[i];
    }
    __syncthreads();

    int cur = 0;
    for (int k0=0; k0<E_; k0+=64) {
        const bool pre = (k0 + 64 < E_);
        if (pre) {   // T14: issue next k-step loads (in flight during compute)
            #pragma unroll
            for (int i=0;i<8;++i)
                px[i] = *(const float4*)(x + (size_t)(row0 + xrow + 16*i)*E_ + (k0+64) + xc4*4);
            #pragma unroll
            for (int i=0;i<4;++i)
                pw[i] = *(const uint4*)(Wslice + (size_t)(wh + 32*i)*2048 + (k0+64)*2 + wcb);
        }

        const unsigned char* sX = smem + cur*32768;
        const unsigned char* sW = sX + 16384;

        #pragma unroll
        for (int ks=0;ks<2;++ks) {
            short8 af[2], bf[8];
            #pragma unroll
            for (int mt=0;mt<2;++mt) {
                int row = w*32 + mt*16 + li;
                af[mt] = *(const short8*)(sX + row*128 + ((ks*64 + grp*16) ^ ((row&7)<<4)));
            }
            #pragma unroll
            for (int nt=0;nt<8;++nt) {
                int rh = nt*16 + li;
                bf[nt] = *(const short8*)(sW + rh*128 + ((ks*64 + grp*16) ^ ((rh&7)<<4)));
            }
            #pragma unroll
            for (int mt=0;mt<2;++mt)
                #pragma unroll
                for (int nt=0;nt<8;++nt)
                    acc[mt][nt] = __builtin_amdgcn_mfma_f32_16x16x32_bf16(af[mt], bf[nt], acc[mt][nt], 0,0,0);
        }

        if (pre) {   // write prefetched k-step into other buffer; ONE barrier/iter
            unsigned char* dX = smem + (cur^1)*32768;
            #pragma unroll
            for (int i=0;i<8;++i) {
                int row = xrow + 16*i;
                uint2 pv;
                pv.x = cvt_pk_bf16(px[i].x, px[i].y);
                pv.y = cvt_pk_bf16(px[i].z, px[i].w);
                *(uint2*)(dX + row*128 + ((xc4*8) ^ ((row&7)<<4))) = pv;
            }
            #pragma unroll
            for (int i=0;i<4;++i) {
                int h = wh + 32*i;
                *(uint4*)(dX + 16384 + h*128 + (wcb ^ ((h&7)<<4))) = pw[i];
            }
            __syncthreads();
            cur ^= 1;
        }
    }

    // epilogue via LDS: stage wave's 32x128 bf16 tile (reuses smem)
    __syncthreads();
    const int base = w * 8704;
    #pragma unroll
    for (int mt=0;mt<2;++mt)
        #pragma unroll
        for (int nt=0;nt<8;++nt)
            #pragma unroll
            for (int r=0;r<4;++r) {
                int rowl = mt*16 + grp*4 + r;
                int col  = nt*16 + li;
                *(unsigned short*)(epi + base + rowl*272 + col*2) = f2bf(acc[mt][nt][r]);
            }
    __syncthreads();

    if (which < 2) {
        unsigned short* O = (which==0)? Qg : Kg;
        #pragma unroll
        for (int i=0;i<8;++i) {
            int idx = i*64 + l;
            int rowl = idx >> 4, cc = idx & 15;
            uint4 v = *(const uint4*)(epi + base + rowl*272 + cc*16);
            int row_g = row0 + w*32 + rowl;
            *(uint4*)((unsigned char*)O + (size_t)row_g*256 + cc*16) = v;
        }
    } else {
        const int bidx = rb >> 5;
        const int srow = (rb & 31) * 128 + w*32;
        #pragma unroll
        for (int i=0;i<8;++i) {
            int idx = i*64 + l;
            int h = idx >> 2, sc = idx & 3;
            uint32_t u[4];
            #pragma unroll
            for (int p=0;p<4;++p) {
                unsigned short a = *(const unsigned short*)(epi + base + (sc*8 + 2*p  )*272 + h*2);
                unsigned short b = *(const unsigned short*)(epi + base + (sc*8 + 2*p+1)*272 + h*2);
                u[p] = (uint32_t)a | ((uint32_t)b << 16);
            }
            uint4 v; v.x=u[0]; v.y=u[1]; v.z=u[2]; v.w=u[3];
            *(uint4*)(Vtg + (size_t)(bidx*H_ + h)*S_ + srow + sc*8) = v;
        }
    }
}

// ---------------- attn pass1: 8 waves x 32q, parity key-split (r9, unchanged) ----------------
__global__ __launch_bounds__(512)
void attn_p1(const unsigned short* __restrict__ Qg,
             const unsigned short* __restrict__ Kg,
             const unsigned short* __restrict__ Vtg,
             float* __restrict__ Pp, float* __restrict__ Ml)
{
    const int t    = threadIdx.x;
    const int w    = t >> 6;
    const int l    = t & 63;
    const int hi   = l >> 5;
    const int c31  = l & 31;
    const int gid  = blockIdx.x;
    const int b    = gid & 7;
    const int rr   = gid >> 3;
    const int cidx = rr & 1;
    const int y    = rr >> 1;
    const int qt   = 15 - y;
    const int q0   = qt * 256;
    const int qw0  = q0 + w*32;
    const int qrow = qw0 + c31;
    const int nkt  = 4*(qt+1);

    __shared__ __align__(128) unsigned char smem[65536];

    const size_t bbase = (size_t)b * S_ * H_;

    short8 qf[8];
    {
        const unsigned short* qp = Qg + bbase + (size_t)qrow * H_;
        #pragma unroll
        for (int ks=0; ks<8; ++ks)
            qf[ks] = *(const short8*)(qp + ks*16 + hi*8);
    }

    f32x16 oacc[4];
    #pragma unroll
    for (int ht=0; ht<4; ++ht)
        #pragma unroll
        for (int r=0; r<16; ++r) oacc[ht][r] = 0.f;
    float mrun = -1e30f, lrun = 0.f;

    const unsigned char* Kb = (const unsigned char*)(Kg + bbase);
    const unsigned char* Vb = (const unsigned char*)(Vtg + (size_t)b*H_*S_);
    const int swzq = (c31 & 7) << 4;

    uint4 rk[2], rv[2];

    #pragma unroll
    for (int i=0;i<2;++i) {
        int c = i*512 + t;
        int row = c >> 4, cb = (c & 15) * 16;
        rk[i] = *(const uint4*)(Kb + (size_t)(cidx*64 + row)*256 + cb);
        int h = c >> 3, cb2 = (c & 7) * 16;
        rv[i] = *(const uint4*)(Vb + (size_t)h*(S_*2) + cidx*128 + cb2);
    }
    #pragma unroll
    for (int i=0;i<2;++i) {
        int c = i*512 + t;
        int row = c >> 4, cb = (c & 15) * 16;
        *(uint4*)(smem + row*256 + (cb ^ ((row&7)<<4))) = rk[i];
        int h = c >> 3, cb2 = (c & 7) * 16;
        *(uint4*)(smem + 16384 + h*128 + (cb2 ^ ((h&7)<<4))) = rv[i];
    }
    __syncthreads();

    int cur = 0;
    for (int kt = cidx; kt < nkt; kt += 2) {
        const bool pre = (kt+2 < nkt);
        if (pre) {
            #pragma unroll
            for (int i=0;i<2;++i) {
                int c = i*512 + t;
                int row = c >> 4, cb = (c & 15) * 16;
                rk[i] = *(const uint4*)(Kb + (size_t)((kt+2)*64 + row)*256 + cb);
                int h = c >> 3, cb2 = (c & 7) * 16;
                rv[i] = *(const uint4*)(Vb + (size_t)h*(S_*2) + (kt+2)*128 + cb2);
            }
        }

        if (kt*64 <= qw0 + 31) {
            const unsigned char* sK = smem + cur*32768;
            const unsigned char* sV = sK + 16384;

            f32x16 sacc[2];
            #pragma unroll
            for (int st=0; st<2; ++st)
                #pragma unroll
                for (int r=0; r<16; ++r) sacc[st][r] = 0.f;
            #pragma unroll
            for (int st=0; st<2; ++st) {
                int krow = st*32 + c31;
                #pragma unroll
                for (int ks=0; ks<8; ++ks) {
                    short8 kf = *(const short8*)(sK + krow*256 + ((ks*32 + hi*16) ^ swzq));
                    sacc[st] = __builtin_amdgcn_mfma_f32_32x32x16_bf16(kf, qf[ks], sacc[st], 0,0,0);
                }
            }

            if (kt*64 + 63 > qw0) {
                #pragma unroll
                for (int st=0; st<2; ++st)
                    #pragma unroll
                    for (int r=0; r<16; ++r) {
                        int key = kt*64 + st*32 + (r&3) + 8*(r>>2) + 4*hi;
                        if (key > qrow) sacc[st][r] = -1e30f;
                    }
            }

            float pmax = -1e30f;
            #pragma unroll
            for (int st=0; st<2; ++st)
                #pragma unroll
                for (int r=0; r<16; ++r) pmax = fmaxf(pmax, sacc[st][r]);
            pmax = fmaxf(pmax, __shfl_xor(pmax, 32, 64));

            if (!__all(pmax - mrun <= 8.0f)) {
                float mnew = fmaxf(mrun, pmax);
                float alpha = __expf(mrun - mnew);
                #pragma unroll
                for (int ht=0; ht<4; ++ht)
                    #pragma unroll
                    for (int r=0; r<16; ++r) oacc[ht][r] *= alpha;
                lrun *= alpha;
                mrun = mnew;
            }

            float p[2][16];
            float psum = 0.f;
            #pragma unroll
            for (int st=0; st<2; ++st)
                #pragma unroll
                for (int r=0; r<16; ++r) {
                    float e = __expf(sacc[st][r] - mrun);
                    p[st][r] = e;
                    psum += e;
                }
            psum += __shfl_xor(psum, 32, 64);
            lrun += psum;

            short8 pf[4];
            #pragma unroll
            for (int st=0; st<2; ++st) {
                uint32_t A0 = cvt_pk_bf16(p[st][0],  p[st][1]);
                uint32_t A1 = cvt_pk_bf16(p[st][2],  p[st][3]);
                uint32_t B0 = cvt_pk_bf16(p[st][4],  p[st][5]);
                uint32_t B1 = cvt_pk_bf16(p[st][6],  p[st][7]);
                uint32_t C0 = cvt_pk_bf16(p[st][8],  p[st][9]);
                uint32_t C1 = cvt_pk_bf16(p[st][10], p[st][11]);
                uint32_t D0 = cvt_pk_bf16(p[st][12], p[st][13]);
                uint32_t D1 = cvt_pk_bf16(p[st][14], p[st][15]);
                {
                    uint32_t x0 = hi ? A0 : B0;
                    uint32_t x1 = hi ? A1 : B1;
                    uint32_t y0 = (uint32_t)__shfl_xor((int)x0, 32, 64);
                    uint32_t y1 = (uint32_t)__shfl_xor((int)x1, 32, 64);
                    union { uint32_t u[4]; short8 s; } uu;
                    uu.u[0] = hi ? y0 : A0;
                    uu.u[1] = hi ? y1 : A1;
                    uu.u[2] = hi ? B0 : y0;
                    uu.u[3] = hi ? B1 : y1;
                    pf[st*2] = uu.s;
                }
                {
                    uint32_t x0 = hi ? C0 : D0;
                    uint32_t x1 = hi ? C1 : D1;
                    uint32_t y0 = (uint32_t)__shfl_xor((int)x0, 32, 64);
                    uint32_t y1 = (uint32_t)__shfl_xor((int)x1, 32, 64);
                    union { uint32_t u[4]; short8 s; } uu;
                    uu.u[0] = hi ? y0 : C0;
                    uu.u[1] = hi ? y1 : C1;
                    uu.u[2] = hi ? D0 : y0;
                    uu.u[3] = hi ? D1 : y1;
                    pf[st*2+1] = uu.s;
                }
            }

            #pragma unroll
            for (int sl=0; sl<4; ++sl) {
                #pragma unroll
                for (int ht=0; ht<4; ++ht) {
                    int h = ht*32 + c31;
                    short8 vf = *(const short8*)(sV + h*128 + ((sl*32 + hi*16) ^ swzq));
                    oacc[ht] = __builtin_amdgcn_mfma_f32_32x32x16_bf16(vf, pf[sl], oacc[ht], 0,0,0);
                }
            }
        }

        if (pre) {
            unsigned char* dK = smem + (cur^1)*32768;
            #pragma unroll
            for (int i=0;i<2;++i) {
                int c = i*512 + t;
                int row = c >> 4, cb = (c & 15) * 16;
                *(uint4*)(dK + row*256 + (cb ^ ((row&7)<<4))) = rk[i];
                int h = c >> 3, cb2 = (c & 7) * 16;
                *(uint4*)(dK + 16384 + h*128 + (cb2 ^ ((h&7)<<4))) = rv[i];
            }
            __syncthreads();
            cur ^= 1;
        }
    }

    float* Prow = Pp + (size_t)cidx*((size_t)M_*H_) + bbase + (size_t)qrow*H_;
    #pragma unroll
    for (int ht=0; ht<4; ++ht)
        #pragma unroll
        for (int k=0; k<4; ++k) {
            float4 o;
            o.x = oacc[ht][4*k+0];
            o.y = oacc[ht][4*k+1];
            o.z = oacc[ht][4*k+2];
            o.w = oacc[ht][4*k+3];
            *(float4*)(Prow + ht*32 + 8*k + 4*hi) = o;
        }
    if (hi == 0) {
        float2 ml2; ml2.x = mrun; ml2.y = lrun;
        *(float2*)(Ml + ((size_t)cidx*M_ + (size_t)b*S_ + qrow)*2) = ml2;
    }
}

// ---------------- merge: renormalize 2 partials (unchanged) ----------------
__global__ __launch_bounds__(256)
void attn_merge(const float* __restrict__ Pp, const float* __restrict__ Ml,
                float* __restrict__ Out)
{
    int gid = blockIdx.x*256 + threadIdx.x;
    int q  = gid >> 5;
    int h4 = gid & 31;

    float m0 = Ml[((size_t)0*M_ + q)*2], l0 = Ml[((size_t)0*M_ + q)*2 + 1];
    float m1 = Ml[((size_t)1*M_ + q)*2], l1 = Ml[((size_t)1*M_ + q)*2 + 1];

    float M = fmaxf(m0, m1);
    float w0 = __expf(m0 - M), w1 = __expf(m1 - M);
    float L = w0*l0 + w1*l1;

    float4 p0 = *(const float4*)(Pp + (size_t)q*H_ + h4*4);
    float4 p1 = *(const float4*)(Pp + (size_t)M_*H_ + (size_t)q*H_ + h4*4);
    float inv = 1.0f / L;
    float4 o;
    o.x = (w0*p0.x + w1*p1.x) * inv;
    o.y = (w0*p0.y + w1*p1.y) * inv;
    o.z = (w0*p0.z + w1*p1.z) * inv;
    o.w = (w0*p0.w + w1*p1.w) * inv;
    *(float4*)(Out + (size_t)q*H_ + h4*4) = o;
}

// ---------------- fallback (v3 single-pass attn) if ws too small ----------------
__global__ __launch_bounds__(128, 1)
void attn_fb(const unsigned short* __restrict__ Qg,
             const unsigned short* __restrict__ Kg,
             const unsigned short* __restrict__ Vtg,
             float* __restrict__ Out)
{
    const int t   = threadIdx.x;
    const int w   = t >> 6;
    const int l   = t & 63;
    const int hi  = l >> 5;
    const int c31 = l & 31;
    const int qt  = (S_/64 - 1) - blockIdx.x;
    const int b   = blockIdx.y;
    const int q0  = qt * 64;
    const int qrow = q0 + w*32 + c31;

    __shared__ __align__(128) unsigned char sK[16384];
    __shared__ __align__(128) unsigned char sV[16384];

    const size_t bbase = (size_t)b * S_ * H_;

    short8 qf[8];
    {
        const unsigned short* qp = Qg + bbase + (size_t)qrow * H_;
        #pragma unroll
        for (int ks=0; ks<8; ++ks)
            qf[ks] = *(const short8*)(qp + ks*16 + hi*8);
    }

    f32x16 oacc[4];
    #pragma unroll
    for (int ht=0; ht<4; ++ht)
        #pragma unroll
        for (int r=0; r<16; ++r) oacc[ht][r] = 0.f;
    float mrun = -1e30f, lrun = 0.f;

    const unsigned char* Kb = (const unsigned char*)(Kg + bbase);
    const unsigned char* Vb = (const unsigned char*)(Vtg + (size_t)b*H_*S_);
    const int swzq = (c31 & 7) << 4;

    for (int kt=0; kt<=qt; ++kt) {
        __syncthreads();
        #pragma unroll
        for (int i=0;i<8;++i) {
            int c = i*128 + t;
            int row = c >> 4, cb = (c & 15) * 16;
            *(uint4*)(sK + row*256 + (cb ^ ((row&7)<<4))) =
                *(const uint4*)(Kb + (size_t)(kt*64 + row)*256 + cb);
        }
        #pragma unroll
        for (int i=0;i<8;++i) {
            int c = i*128 + t;
            int h = c >> 3, cb = (c & 7) * 16;
            *(uint4*)(sV + h*128 + (cb ^ ((h&7)<<4))) =
                *(const uint4*)(Vb + (size_t)h*(S_*2) + kt*128 + cb);
        }
        __syncthreads();

        f32x16 sacc[2];
        #pragma unroll
        for (int st=0; st<2; ++st)
            #pragma unroll
            for (int r=0; r<16; ++r) sacc[st][r] = 0.f;
        #pragma unroll
        for (int st=0; st<2; ++st) {
            int krow = st*32 + c31;
            #pragma unroll
            for (int ks=0; ks<8; ++ks) {
                short8 kf = *(const short8*)(sK + krow*256 + ((ks*32 + hi*16) ^ swzq));
                sacc[st] = __builtin_amdgcn_mfma_f32_32x32x16_bf16(kf, qf[ks], sacc[st], 0,0,0);
            }
        }

        if (kt == qt) {
            #pragma unroll
            for (int st=0; st<2; ++st)
                #pragma unroll
                for (int r=0; r<16; ++r) {
                    int key = q0 + st*32 + (r&3) + 8*(r>>2) + 4*hi;
                    if (key > qrow) sacc[st][r] = -1e30f;
                }
        }

        float pmax = -1e30f;
        #pragma unroll
        for (int st=0; st<2; ++st)
            #pragma unroll
            for (int r=0; r<16; ++r) pmax = fmaxf(pmax, sacc[st][r]);
        pmax = fmaxf(pmax, __shfl_xor(pmax, 32, 64));

        if (!__all(pmax - mrun <= 8.0f)) {
            float mnew = fmaxf(mrun, pmax);
            float alpha = __expf(mrun - mnew);
            #pragma unroll
            for (int ht=0; ht<4; ++ht)
                #pragma unroll
                for (int r=0; r<16; ++r) oacc[ht][r] *= alpha;
            lrun *= alpha;
            mrun = mnew;
        }

        float p[2][16];
        float psum = 0.f;
        #pragma unroll
        for (int st=0; st<2; ++st)
            #pragma unroll
            for (int r=0; r<16; ++r) {
                float e = __expf(sacc[st][r] - mrun);
                p[st][r] = e;
                psum += e;
            }
        psum += __shfl_xor(psum, 32, 64);
        lrun += psum;

        short8 pf[4];
        #pragma unroll
        for (int st=0; st<2; ++st) {
            uint32_t A0 = cvt_pk_bf16(p[st][0],  p[st][1]);
            uint32_t A1 = cvt_pk_bf16(p[st][2],  p[st][3]);
            uint32_t B0 = cvt_pk_bf16(p[st][4],  p[st][5]);
            uint32_t B1 = cvt_pk_bf16(p[st][6],  p[st][7]);
            uint32_t C0 = cvt_pk_bf16(p[st][8],  p[st][9]);
            uint32_t C1 = cvt_pk_bf16(p[st][10], p[st][11]);
            uint32_t D0 = cvt_pk_bf16(p[st][12], p[st][13]);
            uint32_t D1 = cvt_pk_bf16(p[st][14], p[st][15]);
            {
                uint32_t x0 = hi ? A0 : B0;
                uint32_t x1 = hi ? A1 : B1;
                uint32_t y0 = (uint32_t)__shfl_xor((int)x0, 32, 64);
                uint32_t y1 = (uint32_t)__shfl_xor((int)x1, 32, 64);
                union { uint32_t u[4]; short8 s; } uu;
                uu.u[0] = hi ? y0 : A0;
                uu.u[1] = hi ? y1 : A1;
                uu.u[2] = hi ? B0 : y0;
                uu.u[3] = hi ? B1 : y1;
                pf[st*2] = uu.s;
            }
            {
                uint32_t x0 = hi ? C0 : D0;
                uint32_t x1 = hi ? C1 : D1;
                uint32_t y0 = (uint32_t)__shfl_xor((int)x0, 32, 64);
                uint32_t y1 = (uint32_t)__shfl_xor((int)x1, 32, 64);
                union { uint32_t u[4]; short8 s; } uu;
                uu.u[0] = hi ? y0 : C0;
                uu.u[1] = hi ? y1 : C1;
                uu.u[2] = hi ? D0 : y0;
                uu.u[3] = hi ? D1 : y1;
                pf[st*2+1] = uu.s;
            }
        }

        #pragma unroll
        for (int sl=0; sl<4; ++sl) {
            #pragma unroll
            for (int ht=0; ht<4; ++ht) {
                int h = ht*32 + c31;
                short8 vf = *(const short8*)(sV + h*128 + ((sl*32 + hi*16) ^ swzq));
                oacc[ht] = __builtin_amdgcn_mfma_f32_32x32x16_bf16(vf, pf[sl], oacc[ht], 0,0,0);
            }
        }
    }

    float linv = 1.0f / lrun;
    float* Op = Out + bbase + (size_t)qrow * H_;
    #pragma unroll
    for (int ht=0; ht<4; ++ht)
        #pragma unroll
        for (int k=0; k<4; ++k) {
            float4 o;
            o.x = oacc[ht][4*k+0] * linv;
            o.y = oacc[ht][4*k+1] * linv;
            o.z = oacc[ht][4*k+2] * linv;
            o.w = oacc[ht][4*k+3] * linv;
            *(float4*)(Op + ht*32 + 8*k + 4*hi) = o;
        }
}

extern "C" void kernel_launch(void* const* d_in, const int* in_sizes, int n_in,
                              void* d_out, int out_size, void* d_ws, size_t ws_size,
                              hipStream_t stream) {
    const float* x  = (const float*)d_in[0];
    const float* Wq = (const float*)d_in[1];
    const float* Wk = (const float*)d_in[2];
    const float* Wv = (const float*)d_in[3];

    unsigned char* ws = (unsigned char*)d_ws;
    unsigned short* Wt  = (unsigned short*)ws;                          // 768 KB @ 0
    unsigned short* Qg  = (unsigned short*)(ws + 1048576u);             // 8 MB
    unsigned short* Kg  = (unsigned short*)(ws + 9437184u);             // 8 MB
    unsigned short* Vtg = (unsigned short*)(ws + 17825792u);            // 8 MB
    float* Pp = (float*)(ws + 26214400u);                               // 32 MB (2 chunks)
    float* Ml = (float*)(ws + 59768832u);                               // 512 KB
    const size_t NEED = 60293120u;

    prep_w_kernel<<<192, 256, 0, stream>>>(Wq, Wk, Wv, Wt);
    dim3 gp(M_/128, 3);
    proj_kernel<<<gp, 256, 0, stream>>>(x, Wt, Qg, Kg, Vtg);

    if (ws_size >= NEED) {
        attn_p1<<<256, 512, 0, stream>>>(Qg, Kg, Vtg, Pp, Ml);
        attn_merge<<<4096, 256, 0, stream>>>(Pp, Ml, (float*)d_out);
    } else {
        dim3 ga(S_/64, B_);
        attn_fb<<<ga, 128, 0, stream>>>(Qg, Kg, Vtg, (float*)d_out);
    }
}

// Round 11
// 159.969 us; speedup vs baseline: 1.2205x; 1.2205x over previous
//
// v9.0 — FUSED QKV projection: 1 kernel, 256 blocks x 512t (8 waves = 2/SIMD, 1 blk/CU),
//        W-tile = all 3 weights (384x64), per-wave 32rows x 192cols, 2-barrier iters
//        (v8 dbuf regression reverted: conflicts 459K->7.4M from write/read overlap).
//        Attention = r9 winner, unchanged.
#include <hip/hip_runtime.h>
#include <stdint.h>

#define B_ 8
#define S_ 4096
#define E_ 1024
#define H_ 128
#define M_ (B_*S_)

typedef __attribute__((ext_vector_type(8))) short short8;
typedef __attribute__((ext_vector_type(4))) float f32x4;
typedef __attribute__((ext_vector_type(16))) float f32x16;

static constexpr float QSCALE = 0.08838834764831845f; // 1/sqrt(128)

__device__ __forceinline__ unsigned short f2bf(float f) {
    uint32_t u = __float_as_uint(f);
    u += 0x7fffu + ((u >> 16) & 1u);
    return (unsigned short)(u >> 16);
}

__device__ __forceinline__ uint32_t cvt_pk_bf16(float a, float b) {
    uint32_t r;
    asm("v_cvt_pk_bf16_f32 %0, %1, %2" : "=v"(r) : "v"(a), "v"(b));
    return r;
}

// ---------------- W transpose + bf16 convert: Wt[3][128][1024] ----------------
__global__ __launch_bounds__(256)
void prep_w_kernel(const float* __restrict__ Wq, const float* __restrict__ Wk,
                   const float* __restrict__ Wv, unsigned short* __restrict__ Wt)
{
    int id = blockIdx.x*256 + threadIdx.x;
    int which = id >> 14;
    int rem = id & 16383;
    int h = rem >> 7, kc = rem & 127;
    const float* __restrict__ W = (which==0)?Wq:((which==1)?Wk:Wv);
    const float scale = (which==0)? QSCALE : 1.0f;
    uint32_t u[4];
    #pragma unroll
    for (int p=0;p<4;++p) {
        unsigned short a = f2bf(W[(size_t)(kc*8 + 2*p  )*H_ + h] * scale);
        unsigned short b = f2bf(W[(size_t)(kc*8 + 2*p+1)*H_ + h] * scale);
        u[p] = (uint32_t)a | ((uint32_t)b << 16);
    }
    uint4 v; v.x=u[0]; v.y=u[1]; v.z=u[2]; v.w=u[3];
    *(uint4*)(Wt + (size_t)(which*H_ + h)*E_ + kc*8) = v;
}

// ---------------- FUSED QKV projection ----------------
// grid 256 (M_/128), block 512 (8 waves). BM=128, BN=384 (Q|K|V), BK=64.
// wave w: rows rg*32..+32 (rg=w&3), cols cg*192..+192 (cg=w>>2).
__global__ __launch_bounds__(512)
void proj_kernel(const float* __restrict__ x, const unsigned short* __restrict__ Wt,
                 unsigned short* __restrict__ Qg, unsigned short* __restrict__ Kg,
                 unsigned short* __restrict__ Vtg)
{
    const int t = threadIdx.x;
    const int w = t >> 6, l = t & 63;
    const int grp = l >> 4, li = l & 15;
    const int rg = w & 3, cg = w >> 2;
    const int rb = blockIdx.x;
    const int row0 = rb * 128;

    __shared__ __align__(128) unsigned char smem[65536];
    unsigned char* sX = smem;                 // [128][64] bf16, 128B rows, swz
    unsigned char* sW = smem + 16384;         // [384][64] bf16, 128B rows, swz
    unsigned short* epi = (unsigned short*)smem;  // epilogue: [128][208] u16 (53KB)

    f32x4 acc[2][12];
    const f32x4 zz = {0.f,0.f,0.f,0.f};
    #pragma unroll
    for (int mt=0;mt<2;++mt)
        #pragma unroll
        for (int nt=0;nt<12;++nt) acc[mt][nt] = zz;

    for (int k0=0; k0<E_; k0+=64) {
        __syncthreads();
        // stage x tile [128][64] fp32->bf16 (4 float4/thread)
        #pragma unroll
        for (int i=0;i<4;++i) {
            int idx = i*512 + t;
            int row = idx >> 4, c4 = idx & 15;
            float4 v = *(const float4*)(x + (size_t)(row0+row)*E_ + k0 + c4*4);
            uint2 pv;
            pv.x = cvt_pk_bf16(v.x, v.y);
            pv.y = cvt_pk_bf16(v.z, v.w);
            *(uint2*)(sX + row*128 + ((c4*8) ^ ((row&7)<<4))) = pv;
        }
        // stage W tile [384][64] bf16 (6 uint4/thread)
        #pragma unroll
        for (int i=0;i<6;++i) {
            int idx = i*512 + t;
            int wr = idx >> 3, cb = (idx & 7) * 16;
            uint4 v = *(const uint4*)((const unsigned char*)Wt + (size_t)wr*2048 + k0*2 + cb);
            *(uint4*)(sW + wr*128 + (cb ^ ((wr&7)<<4))) = v;
        }
        __syncthreads();

        #pragma unroll
        for (int ks=0;ks<2;++ks) {
            short8 af[2];
            #pragma unroll
            for (int mt=0;mt<2;++mt) {
                int row = rg*32 + mt*16 + li;
                af[mt] = *(const short8*)(sX + row*128 + ((ks*64 + grp*16) ^ ((row&7)<<4)));
            }
            #pragma unroll
            for (int nt=0;nt<12;++nt) {
                int wr = cg*192 + nt*16 + li;
                short8 bf = *(const short8*)(sW + wr*128 + ((ks*64 + grp*16) ^ ((wr&7)<<4)));
                #pragma unroll
                for (int mt=0;mt<2;++mt)
                    acc[mt][nt] = __builtin_amdgcn_mfma_f32_16x16x32_bf16(af[mt], bf, acc[mt][nt], 0,0,0);
            }
        }
    }

    // ---------- epilogue: two LDS-staged passes over col halves ----------
    const int bidx = rb >> 5;                 // batch (32 blocks per batch)
    const int srow = (rb & 31) * 128;         // s base within batch

    __syncthreads();   // last compute done before overwriting smem

    // pass 0: cg==0 waves stage cols 0..191 (Q | K-low)
    if (cg == 0) {
        #pragma unroll
        for (int mt=0;mt<2;++mt)
            #pragma unroll
            for (int nt=0;nt<12;++nt)
                #pragma unroll
                for (int r=0;r<4;++r) {
                    int rowl = rg*32 + mt*16 + grp*4 + r;
                    int col  = nt*16 + li;
                    epi[rowl*208 + col] = f2bf(acc[mt][nt][r]);
                }
    }
    __syncthreads();
    // copy out: Q full rows (cols 0..127)
    #pragma unroll
    for (int i=0;i<4;++i) {
        int idx = i*512 + t;
        int row = idx >> 4, cc = idx & 15;
        uint4 v = *(const uint4*)((const unsigned char*)epi + row*416 + cc*16);
        *(uint4*)((unsigned char*)Qg + (size_t)(row0+row)*256 + cc*16) = v;
    }
    // copy out: K low half (cols 128..191 -> Kg[:,0..63])
    #pragma unroll
    for (int i=0;i<2;++i) {
        int idx = i*512 + t;
        int row = idx >> 3, cc = idx & 7;
        uint4 v = *(const uint4*)((const unsigned char*)epi + row*416 + 256 + cc*16);
        *(uint4*)((unsigned char*)Kg + (size_t)(row0+row)*256 + cc*16) = v;
    }
    __syncthreads();

    // pass 1: cg==1 waves stage cols 192..383 (K-high | V)
    if (cg == 1) {
        #pragma unroll
        for (int mt=0;mt<2;++mt)
            #pragma unroll
            for (int nt=0;nt<12;++nt)
                #pragma unroll
                for (int r=0;r<4;++r) {
                    int rowl = rg*32 + mt*16 + grp*4 + r;
                    int col  = nt*16 + li;
                    epi[rowl*208 + col] = f2bf(acc[mt][nt][r]);
                }
    }
    __syncthreads();
    // copy out: K high half (local cols 0..63 -> Kg[:,64..127])
    #pragma unroll
    for (int i=0;i<2;++i) {
        int idx = i*512 + t;
        int row = idx >> 3, cc = idx & 7;
        uint4 v = *(const uint4*)((const unsigned char*)epi + row*416 + cc*16);
        *(uint4*)((unsigned char*)Kg + (size_t)(row0+row)*256 + 128 + cc*16) = v;
    }
    // copy out: V transposed (local cols 64..191 = h 0..127 -> Vt[b][h][s])
    #pragma unroll
    for (int i=0;i<4;++i) {
        int idx = i*512 + t;
        int h = idx >> 4, sc = idx & 15;
        uint32_t u[4];
        #pragma unroll
        for (int p=0;p<4;++p) {
            unsigned short a = epi[(sc*8 + 2*p    )*208 + 64 + h];
            unsigned short b = epi[(sc*8 + 2*p + 1)*208 + 64 + h];
            u[p] = (uint32_t)a | ((uint32_t)b << 16);
        }
        uint4 v; v.x=u[0]; v.y=u[1]; v.z=u[2]; v.w=u[3];
        *(uint4*)(Vtg + (size_t)(bidx*H_ + h)*S_ + srow + sc*8) = v;
    }
}

// ---------------- attn pass1: 8 waves x 32q, parity key-split (r9, unchanged) ----------------
__global__ __launch_bounds__(512)
void attn_p1(const unsigned short* __restrict__ Qg,
             const unsigned short* __restrict__ Kg,
             const unsigned short* __restrict__ Vtg,
             float* __restrict__ Pp, float* __restrict__ Ml)
{
    const int t    = threadIdx.x;
    const int w    = t >> 6;
    const int l    = t & 63;
    const int hi   = l >> 5;
    const int c31  = l & 31;
    const int gid  = blockIdx.x;
    const int b    = gid & 7;
    const int rr   = gid >> 3;
    const int cidx = rr & 1;
    const int y    = rr >> 1;
    const int qt   = 15 - y;
    const int q0   = qt * 256;
    const int qw0  = q0 + w*32;
    const int qrow = qw0 + c31;
    const int nkt  = 4*(qt+1);

    __shared__ __align__(128) unsigned char smem[65536];

    const size_t bbase = (size_t)b * S_ * H_;

    short8 qf[8];
    {
        const unsigned short* qp = Qg + bbase + (size_t)qrow * H_;
        #pragma unroll
        for (int ks=0; ks<8; ++ks)
            qf[ks] = *(const short8*)(qp + ks*16 + hi*8);
    }

    f32x16 oacc[4];
    #pragma unroll
    for (int ht=0; ht<4; ++ht)
        #pragma unroll
        for (int r=0; r<16; ++r) oacc[ht][r] = 0.f;
    float mrun = -1e30f, lrun = 0.f;

    const unsigned char* Kb = (const unsigned char*)(Kg + bbase);
    const unsigned char* Vb = (const unsigned char*)(Vtg + (size_t)b*H_*S_);
    const int swzq = (c31 & 7) << 4;

    uint4 rk[2], rv[2];

    #pragma unroll
    for (int i=0;i<2;++i) {
        int c = i*512 + t;
        int row = c >> 4, cb = (c & 15) * 16;
        rk[i] = *(const uint4*)(Kb + (size_t)(cidx*64 + row)*256 + cb);
        int h = c >> 3, cb2 = (c & 7) * 16;
        rv[i] = *(const uint4*)(Vb + (size_t)h*(S_*2) + cidx*128 + cb2);
    }
    #pragma unroll
    for (int i=0;i<2;++i) {
        int c = i*512 + t;
        int row = c >> 4, cb = (c & 15) * 16;
        *(uint4*)(smem + row*256 + (cb ^ ((row&7)<<4))) = rk[i];
        int h = c >> 3, cb2 = (c & 7) * 16;
        *(uint4*)(smem + 16384 + h*128 + (cb2 ^ ((h&7)<<4))) = rv[i];
    }
    __syncthreads();

    int cur = 0;
    for (int kt = cidx; kt < nkt; kt += 2) {
        const bool pre = (kt+2 < nkt);
        if (pre) {
            #pragma unroll
            for (int i=0;i<2;++i) {
                int c = i*512 + t;
                int row = c >> 4, cb = (c & 15) * 16;
                rk[i] = *(const uint4*)(Kb + (size_t)((kt+2)*64 + row)*256 + cb);
                int h = c >> 3, cb2 = (c & 7) * 16;
                rv[i] = *(const uint4*)(Vb + (size_t)h*(S_*2) + (kt+2)*128 + cb2);
            }
        }

        if (kt*64 <= qw0 + 31) {
            const unsigned char* sK = smem + cur*32768;
            const unsigned char* sV = sK + 16384;

            f32x16 sacc[2];
            #pragma unroll
            for (int st=0; st<2; ++st)
                #pragma unroll
                for (int r=0; r<16; ++r) sacc[st][r] = 0.f;
            #pragma unroll
            for (int st=0; st<2; ++st) {
                int krow = st*32 + c31;
                #pragma unroll
                for (int ks=0; ks<8; ++ks) {
                    short8 kf = *(const short8*)(sK + krow*256 + ((ks*32 + hi*16) ^ swzq));
                    sacc[st] = __builtin_amdgcn_mfma_f32_32x32x16_bf16(kf, qf[ks], sacc[st], 0,0,0);
                }
            }

            if (kt*64 + 63 > qw0) {
                #pragma unroll
                for (int st=0; st<2; ++st)
                    #pragma unroll
                    for (int r=0; r<16; ++r) {
                        int key = kt*64 + st*32 + (r&3) + 8*(r>>2) + 4*hi;
                        if (key > qrow) sacc[st][r] = -1e30f;
                    }
            }

            float pmax = -1e30f;
            #pragma unroll
            for (int st=0; st<2; ++st)
                #pragma unroll
                for (int r=0; r<16; ++r) pmax = fmaxf(pmax, sacc[st][r]);
            pmax = fmaxf(pmax, __shfl_xor(pmax, 32, 64));

            if (!__all(pmax - mrun <= 8.0f)) {
                float mnew = fmaxf(mrun, pmax);
                float alpha = __expf(mrun - mnew);
                #pragma unroll
                for (int ht=0; ht<4; ++ht)
                    #pragma unroll
                    for (int r=0; r<16; ++r) oacc[ht][r] *= alpha;
                lrun *= alpha;
                mrun = mnew;
            }

            float p[2][16];
            float psum = 0.f;
            #pragma unroll
            for (int st=0; st<2; ++st)
                #pragma unroll
                for (int r=0; r<16; ++r) {
                    float e = __expf(sacc[st][r] - mrun);
                    p[st][r] = e;
                    psum += e;
                }
            psum += __shfl_xor(psum, 32, 64);
            lrun += psum;

            short8 pf[4];
            #pragma unroll
            for (int st=0; st<2; ++st) {
                uint32_t A0 = cvt_pk_bf16(p[st][0],  p[st][1]);
                uint32_t A1 = cvt_pk_bf16(p[st][2],  p[st][3]);
                uint32_t B0 = cvt_pk_bf16(p[st][4],  p[st][5]);
                uint32_t B1 = cvt_pk_bf16(p[st][6],  p[st][7]);
                uint32_t C0 = cvt_pk_bf16(p[st][8],  p[st][9]);
                uint32_t C1 = cvt_pk_bf16(p[st][10], p[st][11]);
                uint32_t D0 = cvt_pk_bf16(p[st][12], p[st][13]);
                uint32_t D1 = cvt_pk_bf16(p[st][14], p[st][15]);
                {
                    uint32_t x0 = hi ? A0 : B0;
                    uint32_t x1 = hi ? A1 : B1;
                    uint32_t y0 = (uint32_t)__shfl_xor((int)x0, 32, 64);
                    uint32_t y1 = (uint32_t)__shfl_xor((int)x1, 32, 64);
                    union { uint32_t u[4]; short8 s; } uu;
                    uu.u[0] = hi ? y0 : A0;
                    uu.u[1] = hi ? y1 : A1;
                    uu.u[2] = hi ? B0 : y0;
                    uu.u[3] = hi ? B1 : y1;
                    pf[st*2] = uu.s;
                }
                {
                    uint32_t x0 = hi ? C0 : D0;
                    uint32_t x1 = hi ? C1 : D1;
                    uint32_t y0 = (uint32_t)__shfl_xor((int)x0, 32, 64);
                    uint32_t y1 = (uint32_t)__shfl_xor((int)x1, 32, 64);
                    union { uint32_t u[4]; short8 s; } uu;
                    uu.u[0] = hi ? y0 : C0;
                    uu.u[1] = hi ? y1 : C1;
                    uu.u[2] = hi ? D0 : y0;
                    uu.u[3] = hi ? D1 : y1;
                    pf[st*2+1] = uu.s;
                }
            }

            #pragma unroll
            for (int sl=0; sl<4; ++sl) {
                #pragma unroll
                for (int ht=0; ht<4; ++ht) {
                    int h = ht*32 + c31;
                    short8 vf = *(const short8*)(sV + h*128 + ((sl*32 + hi*16) ^ swzq));
                    oacc[ht] = __builtin_amdgcn_mfma_f32_32x32x16_bf16(vf, pf[sl], oacc[ht], 0,0,0);
                }
            }
        }

        if (pre) {
            unsigned char* dK = smem + (cur^1)*32768;
            #pragma unroll
            for (int i=0;i<2;++i) {
                int c = i*512 + t;
                int row = c >> 4, cb = (c & 15) * 16;
                *(uint4*)(dK + row*256 + (cb ^ ((row&7)<<4))) = rk[i];
                int h = c >> 3, cb2 = (c & 7) * 16;
                *(uint4*)(dK + 16384 + h*128 + (cb2 ^ ((h&7)<<4))) = rv[i];
            }
            __syncthreads();
            cur ^= 1;
        }
    }

    float* Prow = Pp + (size_t)cidx*((size_t)M_*H_) + bbase + (size_t)qrow*H_;
    #pragma unroll
    for (int ht=0; ht<4; ++ht)
        #pragma unroll
        for (int k=0; k<4; ++k) {
            float4 o;
            o.x = oacc[ht][4*k+0];
            o.y = oacc[ht][4*k+1];
            o.z = oacc[ht][4*k+2];
            o.w = oacc[ht][4*k+3];
            *(float4*)(Prow + ht*32 + 8*k + 4*hi) = o;
        }
    if (hi == 0) {
        float2 ml2; ml2.x = mrun; ml2.y = lrun;
        *(float2*)(Ml + ((size_t)cidx*M_ + (size_t)b*S_ + qrow)*2) = ml2;
    }
}

// ---------------- merge: renormalize 2 partials (unchanged) ----------------
__global__ __launch_bounds__(256)
void attn_merge(const float* __restrict__ Pp, const float* __restrict__ Ml,
                float* __restrict__ Out)
{
    int gid = blockIdx.x*256 + threadIdx.x;
    int q  = gid >> 5;
    int h4 = gid & 31;

    float m0 = Ml[((size_t)0*M_ + q)*2], l0 = Ml[((size_t)0*M_ + q)*2 + 1];
    float m1 = Ml[((size_t)1*M_ + q)*2], l1 = Ml[((size_t)1*M_ + q)*2 + 1];

    float M = fmaxf(m0, m1);
    float w0 = __expf(m0 - M), w1 = __expf(m1 - M);
    float L = w0*l0 + w1*l1;

    float4 p0 = *(const float4*)(Pp + (size_t)q*H_ + h4*4);
    float4 p1 = *(const float4*)(Pp + (size_t)M_*H_ + (size_t)q*H_ + h4*4);
    float inv = 1.0f / L;
    float4 o;
    o.x = (w0*p0.x + w1*p1.x) * inv;
    o.y = (w0*p0.y + w1*p1.y) * inv;
    o.z = (w0*p0.z + w1*p1.z) * inv;
    o.w = (w0*p0.w + w1*p1.w) * inv;
    *(float4*)(Out + (size_t)q*H_ + h4*4) = o;
}

// ---------------- fallback (v3 single-pass attn) if ws too small ----------------
__global__ __launch_bounds__(128, 1)
void attn_fb(const unsigned short* __restrict__ Qg,
             const unsigned short* __restrict__ Kg,
             const unsigned short* __restrict__ Vtg,
             float* __restrict__ Out)
{
    const int t   = threadIdx.x;
    const int w   = t >> 6;
    const int l   = t & 63;
    const int hi  = l >> 5;
    const int c31 = l & 31;
    const int qt  = (S_/64 - 1) - blockIdx.x;
    const int b   = blockIdx.y;
    const int q0  = qt * 64;
    const int qrow = q0 + w*32 + c31;

    __shared__ __align__(128) unsigned char sK[16384];
    __shared__ __align__(128) unsigned char sV[16384];

    const size_t bbase = (size_t)b * S_ * H_;

    short8 qf[8];
    {
        const unsigned short* qp = Qg + bbase + (size_t)qrow * H_;
        #pragma unroll
        for (int ks=0; ks<8; ++ks)
            qf[ks] = *(const short8*)(qp + ks*16 + hi*8);
    }

    f32x16 oacc[4];
    #pragma unroll
    for (int ht=0; ht<4; ++ht)
        #pragma unroll
        for (int r=0; r<16; ++r) oacc[ht][r] = 0.f;
    float mrun = -1e30f, lrun = 0.f;

    const unsigned char* Kb = (const unsigned char*)(Kg + bbase);
    const unsigned char* Vb = (const unsigned char*)(Vtg + (size_t)b*H_*S_);
    const int swzq = (c31 & 7) << 4;

    for (int kt=0; kt<=qt; ++kt) {
        __syncthreads();
        #pragma unroll
        for (int i=0;i<8;++i) {
            int c = i*128 + t;
            int row = c >> 4, cb = (c & 15) * 16;
            *(uint4*)(sK + row*256 + (cb ^ ((row&7)<<4))) =
                *(const uint4*)(Kb + (size_t)(kt*64 + row)*256 + cb);
        }
        #pragma unroll
        for (int i=0;i<8;++i) {
            int c = i*128 + t;
            int h = c >> 3, cb = (c & 7) * 16;
            *(uint4*)(sV + h*128 + (cb ^ ((h&7)<<4))) =
                *(const uint4*)(Vb + (size_t)h*(S_*2) + kt*128 + cb);
        }
        __syncthreads();

        f32x16 sacc[2];
        #pragma unroll
        for (int st=0; st<2; ++st)
            #pragma unroll
            for (int r=0; r<16; ++r) sacc[st][r] = 0.f;
        #pragma unroll
        for (int st=0; st<2; ++st) {
            int krow = st*32 + c31;
            #pragma unroll
            for (int ks=0; ks<8; ++ks) {
                short8 kf = *(const short8*)(sK + krow*256 + ((ks*32 + hi*16) ^ swzq));
                sacc[st] = __builtin_amdgcn_mfma_f32_32x32x16_bf16(kf, qf[ks], sacc[st], 0,0,0);
            }
        }

        if (kt == qt) {
            #pragma unroll
            for (int st=0; st<2; ++st)
                #pragma unroll
                for (int r=0; r<16; ++r) {
                    int key = q0 + st*32 + (r&3) + 8*(r>>2) + 4*hi;
                    if (key > qrow) sacc[st][r] = -1e30f;
                }
        }

        float pmax = -1e30f;
        #pragma unroll
        for (int st=0; st<2; ++st)
            #pragma unroll
            for (int r=0; r<16; ++r) pmax = fmaxf(pmax, sacc[st][r]);
        pmax = fmaxf(pmax, __shfl_xor(pmax, 32, 64));

        if (!__all(pmax - mrun <= 8.0f)) {
            float mnew = fmaxf(mrun, pmax);
            float alpha = __expf(mrun - mnew);
            #pragma unroll
            for (int ht=0; ht<4; ++ht)
                #pragma unroll
                for (int r=0; r<16; ++r) oacc[ht][r] *= alpha;
            lrun *= alpha;
            mrun = mnew;
        }

        float p[2][16];
        float psum = 0.f;
        #pragma unroll
        for (int st=0; st<2; ++st)
            #pragma unroll
            for (int r=0; r<16; ++r) {
                float e = __expf(sacc[st][r] - mrun);
                p[st][r] = e;
                psum += e;
            }
        psum += __shfl_xor(psum, 32, 64);
        lrun += psum;

        short8 pf[4];
        #pragma unroll
        for (int st=0; st<2; ++st) {
            uint32_t A0 = cvt_pk_bf16(p[st][0],  p[st][1]);
            uint32_t A1 = cvt_pk_bf16(p[st][2],  p[st][3]);
            uint32_t B0 = cvt_pk_bf16(p[st][4],  p[st][5]);
            uint32_t B1 = cvt_pk_bf16(p[st][6],  p[st][7]);
            uint32_t C0 = cvt_pk_bf16(p[st][8],  p[st][9]);
            uint32_t C1 = cvt_pk_bf16(p[st][10], p[st][11]);
            uint32_t D0 = cvt_pk_bf16(p[st][12], p[st][13]);
            uint32_t D1 = cvt_pk_bf16(p[st][14], p[st][15]);
            {
                uint32_t x0 = hi ? A0 : B0;
                uint32_t x1 = hi ? A1 : B1;
                uint32_t y0 = (uint32_t)__shfl_xor((int)x0, 32, 64);
                uint32_t y1 = (uint32_t)__shfl_xor((int)x1, 32, 64);
                union { uint32_t u[4]; short8 s; } uu;
                uu.u[0] = hi ? y0 : A0;
                uu.u[1] = hi ? y1 : A1;
                uu.u[2] = hi ? B0 : y0;
                uu.u[3] = hi ? B1 : y1;
                pf[st*2] = uu.s;
            }
            {
                uint32_t x0 = hi ? C0 : D0;
                uint32_t x1 = hi ? C1 : D1;
                uint32_t y0 = (uint32_t)__shfl_xor((int)x0, 32, 64);
                uint32_t y1 = (uint32_t)__shfl_xor((int)x1, 32, 64);
                union { uint32_t u[4]; short8 s; } uu;
                uu.u[0] = hi ? y0 : C0;
                uu.u[1] = hi ? y1 : C1;
                uu.u[2] = hi ? D0 : y0;
                uu.u[3] = hi ? D1 : y1;
                pf[st*2+1] = uu.s;
            }
        }

        #pragma unroll
        for (int sl=0; sl<4; ++sl) {
            #pragma unroll
            for (int ht=0; ht<4; ++ht) {
                int h = ht*32 + c31;
                short8 vf = *(const short8*)(sV + h*128 + ((sl*32 + hi*16) ^ swzq));
                oacc[ht] = __builtin_amdgcn_mfma_f32_32x32x16_bf16(vf, pf[sl], oacc[ht], 0,0,0);
            }
        }
    }

    float linv = 1.0f / lrun;
    float* Op = Out + bbase + (size_t)qrow * H_;
    #pragma unroll
    for (int ht=0; ht<4; ++ht)
        #pragma unroll
        for (int k=0; k<4; ++k) {
            float4 o;
            o.x = oacc[ht][4*k+0] * linv;
            o.y = oacc[ht][4*k+1] * linv;
            o.z = oacc[ht][4*k+2] * linv;
            o.w = oacc[ht][4*k+3] * linv;
            *(float4*)(Op + ht*32 + 8*k + 4*hi) = o;
        }
}

extern "C" void kernel_launch(void* const* d_in, const int* in_sizes, int n_in,
                              void* d_out, int out_size, void* d_ws, size_t ws_size,
                              hipStream_t stream) {
    const float* x  = (const float*)d_in[0];
    const float* Wq = (const float*)d_in[1];
    const float* Wk = (const float*)d_in[2];
    const float* Wv = (const float*)d_in[3];

    unsigned char* ws = (unsigned char*)d_ws;
    unsigned short* Wt  = (unsigned short*)ws;                          // 768 KB @ 0
    unsigned short* Qg  = (unsigned short*)(ws + 1048576u);             // 8 MB
    unsigned short* Kg  = (unsigned short*)(ws + 9437184u);             // 8 MB
    unsigned short* Vtg = (unsigned short*)(ws + 17825792u);            // 8 MB
    float* Pp = (float*)(ws + 26214400u);                               // 32 MB (2 chunks)
    float* Ml = (float*)(ws + 59768832u);                               // 512 KB
    const size_t NEED = 60293120u;

    prep_w_kernel<<<192, 256, 0, stream>>>(Wq, Wk, Wv, Wt);
    proj_kernel<<<256, 512, 0, stream>>>(x, Wt, Qg, Kg, Vtg);

    if (ws_size >= NEED) {
        attn_p1<<<256, 512, 0, stream>>>(Qg, Kg, Vtg, Pp, Ml);
        attn_merge<<<4096, 256, 0, stream>>>(Pp, Ml, (float*)d_out);
    } else {
        dim3 ga(S_/64, B_);
        attn_fb<<<ga, 128, 0, stream>>>(Qg, Kg, Vtg, (float*)d_out);
    }
}

// Round 12
// 158.874 us; speedup vs baseline: 1.2289x; 1.0069x over previous
//
// v9.1 — ONE change vs v9.0: attn_p1 __launch_bounds__(512, 2) to pin regalloc
//        (r11: co-compile flipped attn_p1 to 92 VGPR + scratch traffic, 50->106us).
//        Proj (fused, ~42us) / prep / merge byte-identical.
#include <hip/hip_runtime.h>
#include <stdint.h>

#define B_ 8
#define S_ 4096
#define E_ 1024
#define H_ 128
#define M_ (B_*S_)

typedef __attribute__((ext_vector_type(8))) short short8;
typedef __attribute__((ext_vector_type(4))) float f32x4;
typedef __attribute__((ext_vector_type(16))) float f32x16;

static constexpr float QSCALE = 0.08838834764831845f; // 1/sqrt(128)

__device__ __forceinline__ unsigned short f2bf(float f) {
    uint32_t u = __float_as_uint(f);
    u += 0x7fffu + ((u >> 16) & 1u);
    return (unsigned short)(u >> 16);
}

__device__ __forceinline__ uint32_t cvt_pk_bf16(float a, float b) {
    uint32_t r;
    asm("v_cvt_pk_bf16_f32 %0, %1, %2" : "=v"(r) : "v"(a), "v"(b));
    return r;
}

// ---------------- W transpose + bf16 convert: Wt[3][128][1024] ----------------
__global__ __launch_bounds__(256)
void prep_w_kernel(const float* __restrict__ Wq, const float* __restrict__ Wk,
                   const float* __restrict__ Wv, unsigned short* __restrict__ Wt)
{
    int id = blockIdx.x*256 + threadIdx.x;
    int which = id >> 14;
    int rem = id & 16383;
    int h = rem >> 7, kc = rem & 127;
    const float* __restrict__ W = (which==0)?Wq:((which==1)?Wk:Wv);
    const float scale = (which==0)? QSCALE : 1.0f;
    uint32_t u[4];
    #pragma unroll
    for (int p=0;p<4;++p) {
        unsigned short a = f2bf(W[(size_t)(kc*8 + 2*p  )*H_ + h] * scale);
        unsigned short b = f2bf(W[(size_t)(kc*8 + 2*p+1)*H_ + h] * scale);
        u[p] = (uint32_t)a | ((uint32_t)b << 16);
    }
    uint4 v; v.x=u[0]; v.y=u[1]; v.z=u[2]; v.w=u[3];
    *(uint4*)(Wt + (size_t)(which*H_ + h)*E_ + kc*8) = v;
}

// ---------------- FUSED QKV projection (r11 win, unchanged) ----------------
// grid 256 (M_/128), block 512 (8 waves). BM=128, BN=384 (Q|K|V), BK=64.
__global__ __launch_bounds__(512)
void proj_kernel(const float* __restrict__ x, const unsigned short* __restrict__ Wt,
                 unsigned short* __restrict__ Qg, unsigned short* __restrict__ Kg,
                 unsigned short* __restrict__ Vtg)
{
    const int t = threadIdx.x;
    const int w = t >> 6, l = t & 63;
    const int grp = l >> 4, li = l & 15;
    const int rg = w & 3, cg = w >> 2;
    const int rb = blockIdx.x;
    const int row0 = rb * 128;

    __shared__ __align__(128) unsigned char smem[65536];
    unsigned char* sX = smem;                 // [128][64] bf16, 128B rows, swz
    unsigned char* sW = smem + 16384;         // [384][64] bf16, 128B rows, swz
    unsigned short* epi = (unsigned short*)smem;  // epilogue: [128][208] u16 (53KB)

    f32x4 acc[2][12];
    const f32x4 zz = {0.f,0.f,0.f,0.f};
    #pragma unroll
    for (int mt=0;mt<2;++mt)
        #pragma unroll
        for (int nt=0;nt<12;++nt) acc[mt][nt] = zz;

    for (int k0=0; k0<E_; k0+=64) {
        __syncthreads();
        #pragma unroll
        for (int i=0;i<4;++i) {
            int idx = i*512 + t;
            int row = idx >> 4, c4 = idx & 15;
            float4 v = *(const float4*)(x + (size_t)(row0+row)*E_ + k0 + c4*4);
            uint2 pv;
            pv.x = cvt_pk_bf16(v.x, v.y);
            pv.y = cvt_pk_bf16(v.z, v.w);
            *(uint2*)(sX + row*128 + ((c4*8) ^ ((row&7)<<4))) = pv;
        }
        #pragma unroll
        for (int i=0;i<6;++i) {
            int idx = i*512 + t;
            int wr = idx >> 3, cb = (idx & 7) * 16;
            uint4 v = *(const uint4*)((const unsigned char*)Wt + (size_t)wr*2048 + k0*2 + cb);
            *(uint4*)(sW + wr*128 + (cb ^ ((wr&7)<<4))) = v;
        }
        __syncthreads();

        #pragma unroll
        for (int ks=0;ks<2;++ks) {
            short8 af[2];
            #pragma unroll
            for (int mt=0;mt<2;++mt) {
                int row = rg*32 + mt*16 + li;
                af[mt] = *(const short8*)(sX + row*128 + ((ks*64 + grp*16) ^ ((row&7)<<4)));
            }
            #pragma unroll
            for (int nt=0;nt<12;++nt) {
                int wr = cg*192 + nt*16 + li;
                short8 bf = *(const short8*)(sW + wr*128 + ((ks*64 + grp*16) ^ ((wr&7)<<4)));
                #pragma unroll
                for (int mt=0;mt<2;++mt)
                    acc[mt][nt] = __builtin_amdgcn_mfma_f32_16x16x32_bf16(af[mt], bf, acc[mt][nt], 0,0,0);
            }
        }
    }

    // ---------- epilogue: two LDS-staged passes over col halves ----------
    const int bidx = rb >> 5;
    const int srow = (rb & 31) * 128;

    __syncthreads();

    if (cg == 0) {
        #pragma unroll
        for (int mt=0;mt<2;++mt)
            #pragma unroll
            for (int nt=0;nt<12;++nt)
                #pragma unroll
                for (int r=0;r<4;++r) {
                    int rowl = rg*32 + mt*16 + grp*4 + r;
                    int col  = nt*16 + li;
                    epi[rowl*208 + col] = f2bf(acc[mt][nt][r]);
                }
    }
    __syncthreads();
    #pragma unroll
    for (int i=0;i<4;++i) {
        int idx = i*512 + t;
        int row = idx >> 4, cc = idx & 15;
        uint4 v = *(const uint4*)((const unsigned char*)epi + row*416 + cc*16);
        *(uint4*)((unsigned char*)Qg + (size_t)(row0+row)*256 + cc*16) = v;
    }
    #pragma unroll
    for (int i=0;i<2;++i) {
        int idx = i*512 + t;
        int row = idx >> 3, cc = idx & 7;
        uint4 v = *(const uint4*)((const unsigned char*)epi + row*416 + 256 + cc*16);
        *(uint4*)((unsigned char*)Kg + (size_t)(row0+row)*256 + cc*16) = v;
    }
    __syncthreads();

    if (cg == 1) {
        #pragma unroll
        for (int mt=0;mt<2;++mt)
            #pragma unroll
            for (int nt=0;nt<12;++nt)
                #pragma unroll
                for (int r=0;r<4;++r) {
                    int rowl = rg*32 + mt*16 + grp*4 + r;
                    int col  = nt*16 + li;
                    epi[rowl*208 + col] = f2bf(acc[mt][nt][r]);
                }
    }
    __syncthreads();
    #pragma unroll
    for (int i=0;i<2;++i) {
        int idx = i*512 + t;
        int row = idx >> 3, cc = idx & 7;
        uint4 v = *(const uint4*)((const unsigned char*)epi + row*416 + cc*16);
        *(uint4*)((unsigned char*)Kg + (size_t)(row0+row)*256 + 128 + cc*16) = v;
    }
    #pragma unroll
    for (int i=0;i<4;++i) {
        int idx = i*512 + t;
        int h = idx >> 4, sc = idx & 15;
        uint32_t u[4];
        #pragma unroll
        for (int p=0;p<4;++p) {
            unsigned short a = epi[(sc*8 + 2*p    )*208 + 64 + h];
            unsigned short b = epi[(sc*8 + 2*p + 1)*208 + 64 + h];
            u[p] = (uint32_t)a | ((uint32_t)b << 16);
        }
        uint4 v; v.x=u[0]; v.y=u[1]; v.z=u[2]; v.w=u[3];
        *(uint4*)(Vtg + (size_t)(bidx*H_ + h)*S_ + srow + sc*8) = v;
    }
}

// ---------------- attn pass1: 8 waves x 32q, parity key-split ----------------
// grid 256 (1-D; gid%8 = batch -> XCD pin), block 512.
// (512, 2): pin regalloc at 2 waves/SIMD — r11's co-compile squeezed this
// kernel to 92 VGPR + scratch, doubling its duration.
__global__ __launch_bounds__(512, 2)
void attn_p1(const unsigned short* __restrict__ Qg,
             const unsigned short* __restrict__ Kg,
             const unsigned short* __restrict__ Vtg,
             float* __restrict__ Pp, float* __restrict__ Ml)
{
    const int t    = threadIdx.x;
    const int w    = t >> 6;
    const int l    = t & 63;
    const int hi   = l >> 5;
    const int c31  = l & 31;
    const int gid  = blockIdx.x;
    const int b    = gid & 7;
    const int rr   = gid >> 3;
    const int cidx = rr & 1;
    const int y    = rr >> 1;
    const int qt   = 15 - y;
    const int q0   = qt * 256;
    const int qw0  = q0 + w*32;
    const int qrow = qw0 + c31;
    const int nkt  = 4*(qt+1);

    __shared__ __align__(128) unsigned char smem[65536];

    const size_t bbase = (size_t)b * S_ * H_;

    short8 qf[8];
    {
        const unsigned short* qp = Qg + bbase + (size_t)qrow * H_;
        #pragma unroll
        for (int ks=0; ks<8; ++ks)
            qf[ks] = *(const short8*)(qp + ks*16 + hi*8);
    }

    f32x16 oacc[4];
    #pragma unroll
    for (int ht=0; ht<4; ++ht)
        #pragma unroll
        for (int r=0; r<16; ++r) oacc[ht][r] = 0.f;
    float mrun = -1e30f, lrun = 0.f;

    const unsigned char* Kb = (const unsigned char*)(Kg + bbase);
    const unsigned char* Vb = (const unsigned char*)(Vtg + (size_t)b*H_*S_);
    const int swzq = (c31 & 7) << 4;

    uint4 rk[2], rv[2];

    #pragma unroll
    for (int i=0;i<2;++i) {
        int c = i*512 + t;
        int row = c >> 4, cb = (c & 15) * 16;
        rk[i] = *(const uint4*)(Kb + (size_t)(cidx*64 + row)*256 + cb);
        int h = c >> 3, cb2 = (c & 7) * 16;
        rv[i] = *(const uint4*)(Vb + (size_t)h*(S_*2) + cidx*128 + cb2);
    }
    #pragma unroll
    for (int i=0;i<2;++i) {
        int c = i*512 + t;
        int row = c >> 4, cb = (c & 15) * 16;
        *(uint4*)(smem + row*256 + (cb ^ ((row&7)<<4))) = rk[i];
        int h = c >> 3, cb2 = (c & 7) * 16;
        *(uint4*)(smem + 16384 + h*128 + (cb2 ^ ((h&7)<<4))) = rv[i];
    }
    __syncthreads();

    int cur = 0;
    for (int kt = cidx; kt < nkt; kt += 2) {
        const bool pre = (kt+2 < nkt);
        if (pre) {
            #pragma unroll
            for (int i=0;i<2;++i) {
                int c = i*512 + t;
                int row = c >> 4, cb = (c & 15) * 16;
                rk[i] = *(const uint4*)(Kb + (size_t)((kt+2)*64 + row)*256 + cb);
                int h = c >> 3, cb2 = (c & 7) * 16;
                rv[i] = *(const uint4*)(Vb + (size_t)h*(S_*2) + (kt+2)*128 + cb2);
            }
        }

        if (kt*64 <= qw0 + 31) {
            const unsigned char* sK = smem + cur*32768;
            const unsigned char* sV = sK + 16384;

            f32x16 sacc[2];
            #pragma unroll
            for (int st=0; st<2; ++st)
                #pragma unroll
                for (int r=0; r<16; ++r) sacc[st][r] = 0.f;
            #pragma unroll
            for (int st=0; st<2; ++st) {
                int krow = st*32 + c31;
                #pragma unroll
                for (int ks=0; ks<8; ++ks) {
                    short8 kf = *(const short8*)(sK + krow*256 + ((ks*32 + hi*16) ^ swzq));
                    sacc[st] = __builtin_amdgcn_mfma_f32_32x32x16_bf16(kf, qf[ks], sacc[st], 0,0,0);
                }
            }

            if (kt*64 + 63 > qw0) {
                #pragma unroll
                for (int st=0; st<2; ++st)
                    #pragma unroll
                    for (int r=0; r<16; ++r) {
                        int key = kt*64 + st*32 + (r&3) + 8*(r>>2) + 4*hi;
                        if (key > qrow) sacc[st][r] = -1e30f;
                    }
            }

            float pmax = -1e30f;
            #pragma unroll
            for (int st=0; st<2; ++st)
                #pragma unroll
                for (int r=0; r<16; ++r) pmax = fmaxf(pmax, sacc[st][r]);
            pmax = fmaxf(pmax, __shfl_xor(pmax, 32, 64));

            if (!__all(pmax - mrun <= 8.0f)) {
                float mnew = fmaxf(mrun, pmax);
                float alpha = __expf(mrun - mnew);
                #pragma unroll
                for (int ht=0; ht<4; ++ht)
                    #pragma unroll
                    for (int r=0; r<16; ++r) oacc[ht][r] *= alpha;
                lrun *= alpha;
                mrun = mnew;
            }

            float p[2][16];
            float psum = 0.f;
            #pragma unroll
            for (int st=0; st<2; ++st)
                #pragma unroll
                for (int r=0; r<16; ++r) {
                    float e = __expf(sacc[st][r] - mrun);
                    p[st][r] = e;
                    psum += e;
                }
            psum += __shfl_xor(psum, 32, 64);
            lrun += psum;

            short8 pf[4];
            #pragma unroll
            for (int st=0; st<2; ++st) {
                uint32_t A0 = cvt_pk_bf16(p[st][0],  p[st][1]);
                uint32_t A1 = cvt_pk_bf16(p[st][2],  p[st][3]);
                uint32_t B0 = cvt_pk_bf16(p[st][4],  p[st][5]);
                uint32_t B1 = cvt_pk_bf16(p[st][6],  p[st][7]);
                uint32_t C0 = cvt_pk_bf16(p[st][8],  p[st][9]);
                uint32_t C1 = cvt_pk_bf16(p[st][10], p[st][11]);
                uint32_t D0 = cvt_pk_bf16(p[st][12], p[st][13]);
                uint32_t D1 = cvt_pk_bf16(p[st][14], p[st][15]);
                {
                    uint32_t x0 = hi ? A0 : B0;
                    uint32_t x1 = hi ? A1 : B1;
                    uint32_t y0 = (uint32_t)__shfl_xor((int)x0, 32, 64);
                    uint32_t y1 = (uint32_t)__shfl_xor((int)x1, 32, 64);
                    union { uint32_t u[4]; short8 s; } uu;
                    uu.u[0] = hi ? y0 : A0;
                    uu.u[1] = hi ? y1 : A1;
                    uu.u[2] = hi ? B0 : y0;
                    uu.u[3] = hi ? B1 : y1;
                    pf[st*2] = uu.s;
                }
                {
                    uint32_t x0 = hi ? C0 : D0;
                    uint32_t x1 = hi ? C1 : D1;
                    uint32_t y0 = (uint32_t)__shfl_xor((int)x0, 32, 64);
                    uint32_t y1 = (uint32_t)__shfl_xor((int)x1, 32, 64);
                    union { uint32_t u[4]; short8 s; } uu;
                    uu.u[0] = hi ? y0 : C0;
                    uu.u[1] = hi ? y1 : C1;
                    uu.u[2] = hi ? D0 : y0;
                    uu.u[3] = hi ? D1 : y1;
                    pf[st*2+1] = uu.s;
                }
            }

            #pragma unroll
            for (int sl=0; sl<4; ++sl) {
                #pragma unroll
                for (int ht=0; ht<4; ++ht) {
                    int h = ht*32 + c31;
                    short8 vf = *(const short8*)(sV + h*128 + ((sl*32 + hi*16) ^ swzq));
                    oacc[ht] = __builtin_amdgcn_mfma_f32_32x32x16_bf16(vf, pf[sl], oacc[ht], 0,0,0);
                }
            }
        }

        if (pre) {
            unsigned char* dK = smem + (cur^1)*32768;
            #pragma unroll
            for (int i=0;i<2;++i) {
                int c = i*512 + t;
                int row = c >> 4, cb = (c & 15) * 16;
                *(uint4*)(dK + row*256 + (cb ^ ((row&7)<<4))) = rk[i];
                int h = c >> 3, cb2 = (c & 7) * 16;
                *(uint4*)(dK + 16384 + h*128 + (cb2 ^ ((h&7)<<4))) = rv[i];
            }
            __syncthreads();
            cur ^= 1;
        }
    }

    float* Prow = Pp + (size_t)cidx*((size_t)M_*H_) + bbase + (size_t)qrow*H_;
    #pragma unroll
    for (int ht=0; ht<4; ++ht)
        #pragma unroll
        for (int k=0; k<4; ++k) {
            float4 o;
            o.x = oacc[ht][4*k+0];
            o.y = oacc[ht][4*k+1];
            o.z = oacc[ht][4*k+2];
            o.w = oacc[ht][4*k+3];
            *(float4*)(Prow + ht*32 + 8*k + 4*hi) = o;
        }
    if (hi == 0) {
        float2 ml2; ml2.x = mrun; ml2.y = lrun;
        *(float2*)(Ml + ((size_t)cidx*M_ + (size_t)b*S_ + qrow)*2) = ml2;
    }
}

// ---------------- merge: renormalize 2 partials (unchanged) ----------------
__global__ __launch_bounds__(256)
void attn_merge(const float* __restrict__ Pp, const float* __restrict__ Ml,
                float* __restrict__ Out)
{
    int gid = blockIdx.x*256 + threadIdx.x;
    int q  = gid >> 5;
    int h4 = gid & 31;

    float m0 = Ml[((size_t)0*M_ + q)*2], l0 = Ml[((size_t)0*M_ + q)*2 + 1];
    float m1 = Ml[((size_t)1*M_ + q)*2], l1 = Ml[((size_t)1*M_ + q)*2 + 1];

    float M = fmaxf(m0, m1);
    float w0 = __expf(m0 - M), w1 = __expf(m1 - M);
    float L = w0*l0 + w1*l1;

    float4 p0 = *(const float4*)(Pp + (size_t)q*H_ + h4*4);
    float4 p1 = *(const float4*)(Pp + (size_t)M_*H_ + (size_t)q*H_ + h4*4);
    float inv = 1.0f / L;
    float4 o;
    o.x = (w0*p0.x + w1*p1.x) * inv;
    o.y = (w0*p0.y + w1*p1.y) * inv;
    o.z = (w0*p0.z + w1*p1.z) * inv;
    o.w = (w0*p0.w + w1*p1.w) * inv;
    *(float4*)(Out + (size_t)q*H_ + h4*4) = o;
}

// ---------------- fallback (v3 single-pass attn) if ws too small ----------------
__global__ __launch_bounds__(128, 1)
void attn_fb(const unsigned short* __restrict__ Qg,
             const unsigned short* __restrict__ Kg,
             const unsigned short* __restrict__ Vtg,
             float* __restrict__ Out)
{
    const int t   = threadIdx.x;
    const int w   = t >> 6;
    const int l   = t & 63;
    const int hi  = l >> 5;
    const int c31 = l & 31;
    const int qt  = (S_/64 - 1) - blockIdx.x;
    const int b   = blockIdx.y;
    const int q0  = qt * 64;
    const int qrow = q0 + w*32 + c31;

    __shared__ __align__(128) unsigned char sK[16384];
    __shared__ __align__(128) unsigned char sV[16384];

    const size_t bbase = (size_t)b * S_ * H_;

    short8 qf[8];
    {
        const unsigned short* qp = Qg + bbase + (size_t)qrow * H_;
        #pragma unroll
        for (int ks=0; ks<8; ++ks)
            qf[ks] = *(const short8*)(qp + ks*16 + hi*8);
    }

    f32x16 oacc[4];
    #pragma unroll
    for (int ht=0; ht<4; ++ht)
        #pragma unroll
        for (int r=0; r<16; ++r) oacc[ht][r] = 0.f;
    float mrun = -1e30f, lrun = 0.f;

    const unsigned char* Kb = (const unsigned char*)(Kg + bbase);
    const unsigned char* Vb = (const unsigned char*)(Vtg + (size_t)b*H_*S_);
    const int swzq = (c31 & 7) << 4;

    for (int kt=0; kt<=qt; ++kt) {
        __syncthreads();
        #pragma unroll
        for (int i=0;i<8;++i) {
            int c = i*128 + t;
            int row = c >> 4, cb = (c & 15) * 16;
            *(uint4*)(sK + row*256 + (cb ^ ((row&7)<<4))) =
                *(const uint4*)(Kb + (size_t)(kt*64 + row)*256 + cb);
        }
        #pragma unroll
        for (int i=0;i<8;++i) {
            int c = i*128 + t;
            int h = c >> 3, cb = (c & 7) * 16;
            *(uint4*)(sV + h*128 + (cb ^ ((h&7)<<4))) =
                *(const uint4*)(Vb + (size_t)h*(S_*2) + kt*128 + cb);
        }
        __syncthreads();

        f32x16 sacc[2];
        #pragma unroll
        for (int st=0; st<2; ++st)
            #pragma unroll
            for (int r=0; r<16; ++r) sacc[st][r] = 0.f;
        #pragma unroll
        for (int st=0; st<2; ++st) {
            int krow = st*32 + c31;
            #pragma unroll
            for (int ks=0; ks<8; ++ks) {
                short8 kf = *(const short8*)(sK + krow*256 + ((ks*32 + hi*16) ^ swzq));
                sacc[st] = __builtin_amdgcn_mfma_f32_32x32x16_bf16(kf, qf[ks], sacc[st], 0,0,0);
            }
        }

        if (kt == qt) {
            #pragma unroll
            for (int st=0; st<2; ++st)
                #pragma unroll
                for (int r=0; r<16; ++r) {
                    int key = q0 + st*32 + (r&3) + 8*(r>>2) + 4*hi;
                    if (key > qrow) sacc[st][r] = -1e30f;
                }
        }

        float pmax = -1e30f;
        #pragma unroll
        for (int st=0; st<2; ++st)
            #pragma unroll
            for (int r=0; r<16; ++r) pmax = fmaxf(pmax, sacc[st][r]);
        pmax = fmaxf(pmax, __shfl_xor(pmax, 32, 64));

        if (!__all(pmax - mrun <= 8.0f)) {
            float mnew = fmaxf(mrun, pmax);
            float alpha = __expf(mrun - mnew);
            #pragma unroll
            for (int ht=0; ht<4; ++ht)
                #pragma unroll
                for (int r=0; r<16; ++r) oacc[ht][r] *= alpha;
            lrun *= alpha;
            mrun = mnew;
        }

        float p[2][16];
        float psum = 0.f;
        #pragma unroll
        for (int st=0; st<2; ++st)
            #pragma unroll
            for (int r=0; r<16; ++r) {
                float e = __expf(sacc[st][r] - mrun);
                p[st][r] = e;
                psum += e;
            }
        psum += __shfl_xor(psum, 32, 64);
        lrun += psum;

        short8 pf[4];
        #pragma unroll
        for (int st=0; st<2; ++st) {
            uint32_t A0 = cvt_pk_bf16(p[st][0],  p[st][1]);
            uint32_t A1 = cvt_pk_bf16(p[st][2],  p[st][3]);
            uint32_t B0 = cvt_pk_bf16(p[st][4],  p[st][5]);
            uint32_t B1 = cvt_pk_bf16(p[st][6],  p[st][7]);
            uint32_t C0 = cvt_pk_bf16(p[st][8],  p[st][9]);
            uint32_t C1 = cvt_pk_bf16(p[st][10], p[st][11]);
            uint32_t D0 = cvt_pk_bf16(p[st][12], p[st][13]);
            uint32_t D1 = cvt_pk_bf16(p[st][14], p[st][15]);
            {
                uint32_t x0 = hi ? A0 : B0;
                uint32_t x1 = hi ? A1 : B1;
                uint32_t y0 = (uint32_t)__shfl_xor((int)x0, 32, 64);
                uint32_t y1 = (uint32_t)__shfl_xor((int)x1, 32, 64);
                union { uint32_t u[4]; short8 s; } uu;
                uu.u[0] = hi ? y0 : A0;
                uu.u[1] = hi ? y1 : A1;
                uu.u[2] = hi ? B0 : y0;
                uu.u[3] = hi ? B1 : y1;
                pf[st*2] = uu.s;
            }
            {
                uint32_t x0 = hi ? C0 : D0;
                uint32_t x1 = hi ? C1 : D1;
                uint32_t y0 = (uint32_t)__shfl_xor((int)x0, 32, 64);
                uint32_t y1 = (uint32_t)__shfl_xor((int)x1, 32, 64);
                union { uint32_t u[4]; short8 s; } uu;
                uu.u[0] = hi ? y0 : C0;
                uu.u[1] = hi ? y1 : C1;
                uu.u[2] = hi ? D0 : y0;
                uu.u[3] = hi ? D1 : y1;
                pf[st*2+1] = uu.s;
            }
        }

        #pragma unroll
        for (int sl=0; sl<4; ++sl) {
            #pragma unroll
            for (int ht=0; ht<4; ++ht) {
                int h = ht*32 + c31;
                short8 vf = *(const short8*)(sV + h*128 + ((sl*32 + hi*16) ^ swzq));
                oacc[ht] = __builtin_amdgcn_mfma_f32_32x32x16_bf16(vf, pf[sl], oacc[ht], 0,0,0);
            }
        }
    }

    float linv = 1.0f / lrun;
    float* Op = Out + bbase + (size_t)qrow * H_;
    #pragma unroll
    for (int ht=0; ht<4; ++ht)
        #pragma unroll
        for (int k=0; k<4; ++k) {
            float4 o;
            o.x = oacc[ht][4*k+0] * linv;
            o.y = oacc[ht][4*k+1] * linv;
            o.z = oacc[ht][4*k+2] * linv;
            o.w = oacc[ht][4*k+3] * linv;
            *(float4*)(Op + ht*32 + 8*k + 4*hi) = o;
        }
}

extern "C" void kernel_launch(void* const* d_in, const int* in_sizes, int n_in,
                              void* d_out, int out_size, void* d_ws, size_t ws_size,
                              hipStream_t stream) {
    const float* x  = (const float*)d_in[0];
    const float* Wq = (const float*)d_in[1];
    const float* Wk = (const float*)d_in[2];
    const float* Wv = (const float*)d_in[3];

    unsigned char* ws = (unsigned char*)d_ws;
    unsigned short* Wt  = (unsigned short*)ws;                          // 768 KB @ 0
    unsigned short* Qg  = (unsigned short*)(ws + 1048576u);             // 8 MB
    unsigned short* Kg  = (unsigned short*)(ws + 9437184u);             // 8 MB
    unsigned short* Vtg = (unsigned short*)(ws + 17825792u);            // 8 MB
    float* Pp = (float*)(ws + 26214400u);                               // 32 MB (2 chunks)
    float* Ml = (float*)(ws + 59768832u);                               // 512 KB
    const size_t NEED = 60293120u;

    prep_w_kernel<<<192, 256, 0, stream>>>(Wq, Wk, Wv, Wt);
    proj_kernel<<<256, 512, 0, stream>>>(x, Wt, Qg, Kg, Vtg);

    if (ws_size >= NEED) {
        attn_p1<<<256, 512, 0, stream>>>(Qg, Kg, Vtg, Pp, Ml);
        attn_merge<<<4096, 256, 0, stream>>>(Pp, Ml, (float*)d_out);
    } else {
        dim3 ga(S_/64, B_);
        attn_fb<<<ga, 128, 0, stream>>>(Qg, Kg, Vtg, (float*)d_out);
    }
}

// Round 13
// 120.752 us; speedup vs baseline: 1.6169x; 1.3157x over previous
//
// v10.0 — attn_p1: 4-way parity key-split + paired q-tiles (qt=pr, 15-pr) = uniform
//         17 iters/block (was 2..32, 47% idle); staging via global_load_lds with
//         pre-swizzled global source (no reg prefetch left to mis-schedule).
//         Merge: 4 chunks. Proj/prep unchanged (r11 win).
#include <hip/hip_runtime.h>
#include <stdint.h>

#define B_ 8
#define S_ 4096
#define E_ 1024
#define H_ 128
#define M_ (B_*S_)

typedef __attribute__((ext_vector_type(8))) short short8;
typedef __attribute__((ext_vector_type(4))) float f32x4;
typedef __attribute__((ext_vector_type(16))) float f32x16;

static constexpr float QSCALE = 0.08838834764831845f; // 1/sqrt(128)

__device__ __forceinline__ unsigned short f2bf(float f) {
    uint32_t u = __float_as_uint(f);
    u += 0x7fffu + ((u >> 16) & 1u);
    return (unsigned short)(u >> 16);
}

__device__ __forceinline__ uint32_t cvt_pk_bf16(float a, float b) {
    uint32_t r;
    asm("v_cvt_pk_bf16_f32 %0, %1, %2" : "=v"(r) : "v"(a), "v"(b));
    return r;
}

__device__ __forceinline__ void gl16(const void* g, void* s) {
    __builtin_amdgcn_global_load_lds(
        (const __attribute__((address_space(1))) unsigned int*)g,
        (__attribute__((address_space(3))) unsigned int*)s, 16, 0, 0);
}

// ---------------- W transpose + bf16 convert: Wt[3][128][1024] ----------------
__global__ __launch_bounds__(256)
void prep_w_kernel(const float* __restrict__ Wq, const float* __restrict__ Wk,
                   const float* __restrict__ Wv, unsigned short* __restrict__ Wt)
{
    int id = blockIdx.x*256 + threadIdx.x;
    int which = id >> 14;
    int rem = id & 16383;
    int h = rem >> 7, kc = rem & 127;
    const float* __restrict__ W = (which==0)?Wq:((which==1)?Wk:Wv);
    const float scale = (which==0)? QSCALE : 1.0f;
    uint32_t u[4];
    #pragma unroll
    for (int p=0;p<4;++p) {
        unsigned short a = f2bf(W[(size_t)(kc*8 + 2*p  )*H_ + h] * scale);
        unsigned short b = f2bf(W[(size_t)(kc*8 + 2*p+1)*H_ + h] * scale);
        u[p] = (uint32_t)a | ((uint32_t)b << 16);
    }
    uint4 v; v.x=u[0]; v.y=u[1]; v.z=u[2]; v.w=u[3];
    *(uint4*)(Wt + (size_t)(which*H_ + h)*E_ + kc*8) = v;
}

// ---------------- FUSED QKV projection (r11 win, unchanged) ----------------
__global__ __launch_bounds__(512)
void proj_kernel(const float* __restrict__ x, const unsigned short* __restrict__ Wt,
                 unsigned short* __restrict__ Qg, unsigned short* __restrict__ Kg,
                 unsigned short* __restrict__ Vtg)
{
    const int t = threadIdx.x;
    const int w = t >> 6, l = t & 63;
    const int grp = l >> 4, li = l & 15;
    const int rg = w & 3, cg = w >> 2;
    const int rb = blockIdx.x;
    const int row0 = rb * 128;

    __shared__ __align__(128) unsigned char smem[65536];
    unsigned char* sX = smem;
    unsigned char* sW = smem + 16384;
    unsigned short* epi = (unsigned short*)smem;

    f32x4 acc[2][12];
    const f32x4 zz = {0.f,0.f,0.f,0.f};
    #pragma unroll
    for (int mt=0;mt<2;++mt)
        #pragma unroll
        for (int nt=0;nt<12;++nt) acc[mt][nt] = zz;

    for (int k0=0; k0<E_; k0+=64) {
        __syncthreads();
        #pragma unroll
        for (int i=0;i<4;++i) {
            int idx = i*512 + t;
            int row = idx >> 4, c4 = idx & 15;
            float4 v = *(const float4*)(x + (size_t)(row0+row)*E_ + k0 + c4*4);
            uint2 pv;
            pv.x = cvt_pk_bf16(v.x, v.y);
            pv.y = cvt_pk_bf16(v.z, v.w);
            *(uint2*)(sX + row*128 + ((c4*8) ^ ((row&7)<<4))) = pv;
        }
        #pragma unroll
        for (int i=0;i<6;++i) {
            int idx = i*512 + t;
            int wr = idx >> 3, cb = (idx & 7) * 16;
            uint4 v = *(const uint4*)((const unsigned char*)Wt + (size_t)wr*2048 + k0*2 + cb);
            *(uint4*)(sW + wr*128 + (cb ^ ((wr&7)<<4))) = v;
        }
        __syncthreads();

        #pragma unroll
        for (int ks=0;ks<2;++ks) {
            short8 af[2];
            #pragma unroll
            for (int mt=0;mt<2;++mt) {
                int row = rg*32 + mt*16 + li;
                af[mt] = *(const short8*)(sX + row*128 + ((ks*64 + grp*16) ^ ((row&7)<<4)));
            }
            #pragma unroll
            for (int nt=0;nt<12;++nt) {
                int wr = cg*192 + nt*16 + li;
                short8 bf = *(const short8*)(sW + wr*128 + ((ks*64 + grp*16) ^ ((wr&7)<<4)));
                #pragma unroll
                for (int mt=0;mt<2;++mt)
                    acc[mt][nt] = __builtin_amdgcn_mfma_f32_16x16x32_bf16(af[mt], bf, acc[mt][nt], 0,0,0);
            }
        }
    }

    const int bidx = rb >> 5;
    const int srow = (rb & 31) * 128;

    __syncthreads();

    if (cg == 0) {
        #pragma unroll
        for (int mt=0;mt<2;++mt)
            #pragma unroll
            for (int nt=0;nt<12;++nt)
                #pragma unroll
                for (int r=0;r<4;++r) {
                    int rowl = rg*32 + mt*16 + grp*4 + r;
                    int col  = nt*16 + li;
                    epi[rowl*208 + col] = f2bf(acc[mt][nt][r]);
                }
    }
    __syncthreads();
    #pragma unroll
    for (int i=0;i<4;++i) {
        int idx = i*512 + t;
        int row = idx >> 4, cc = idx & 15;
        uint4 v = *(const uint4*)((const unsigned char*)epi + row*416 + cc*16);
        *(uint4*)((unsigned char*)Qg + (size_t)(row0+row)*256 + cc*16) = v;
    }
    #pragma unroll
    for (int i=0;i<2;++i) {
        int idx = i*512 + t;
        int row = idx >> 3, cc = idx & 7;
        uint4 v = *(const uint4*)((const unsigned char*)epi + row*416 + 256 + cc*16);
        *(uint4*)((unsigned char*)Kg + (size_t)(row0+row)*256 + cc*16) = v;
    }
    __syncthreads();

    if (cg == 1) {
        #pragma unroll
        for (int mt=0;mt<2;++mt)
            #pragma unroll
            for (int nt=0;nt<12;++nt)
                #pragma unroll
                for (int r=0;r<4;++r) {
                    int rowl = rg*32 + mt*16 + grp*4 + r;
                    int col  = nt*16 + li;
                    epi[rowl*208 + col] = f2bf(acc[mt][nt][r]);
                }
    }
    __syncthreads();
    #pragma unroll
    for (int i=0;i<2;++i) {
        int idx = i*512 + t;
        int row = idx >> 3, cc = idx & 7;
        uint4 v = *(const uint4*)((const unsigned char*)epi + row*416 + cc*16);
        *(uint4*)((unsigned char*)Kg + (size_t)(row0+row)*256 + 128 + cc*16) = v;
    }
    #pragma unroll
    for (int i=0;i<4;++i) {
        int idx = i*512 + t;
        int h = idx >> 4, sc = idx & 15;
        uint32_t u[4];
        #pragma unroll
        for (int p=0;p<4;++p) {
            unsigned short a = epi[(sc*8 + 2*p    )*208 + 64 + h];
            unsigned short b = epi[(sc*8 + 2*p + 1)*208 + 64 + h];
            u[p] = (uint32_t)a | ((uint32_t)b << 16);
        }
        uint4 v; v.x=u[0]; v.y=u[1]; v.z=u[2]; v.w=u[3];
        *(uint4*)(Vtg + (size_t)(bidx*H_ + h)*S_ + srow + sc*8) = v;
    }
}

// ---- async stage of one 64-key tile (K 16KB + Vt 16KB) via global_load_lds ----
// Pre-swizzled global source; LDS dest linear per wave. 4 instrs/wave.
__device__ __forceinline__ void stage_tile(unsigned char* buf,
                                           const unsigned char* Kb,
                                           const unsigned char* Vb,
                                           int kt, int w, int l)
{
    unsigned char* sVb = buf + 16384;
    #pragma unroll
    for (int j=0;j<2;++j) {
        int A = w*2048 + j*1024 + (l<<4);
        int krow = A >> 8;
        int kin  = A & 255;
        gl16(Kb + (size_t)kt*16384 + krow*256 + (kin ^ ((krow&7)<<4)),
             buf + w*2048 + j*1024);
        int h   = A >> 7;
        int vin = A & 127;
        gl16(Vb + (size_t)h*8192 + (size_t)kt*128 + (vin ^ ((h&7)<<4)),
             sVb + w*2048 + j*1024);
    }
}

// ---------------- attn pass1: paired q-tiles, 4-way parity split ----------------
// grid 256 (gid%8=batch -> XCD pin; rr>>2 = pair, rr&3 = chunk), block 512.
// Every block: exactly 17 iterations (qt=pr then qt=15-pr).
__global__ __launch_bounds__(512, 2)
void attn_p1(const unsigned short* __restrict__ Qg,
             const unsigned short* __restrict__ Kg,
             const unsigned short* __restrict__ Vtg,
             float* __restrict__ Pp, float* __restrict__ Ml)
{
    const int t    = threadIdx.x;
    const int w    = t >> 6;
    const int l    = t & 63;
    const int hi   = l >> 5;
    const int c31  = l & 31;
    const int gid  = blockIdx.x;
    const int b    = gid & 7;
    const int rr   = gid >> 3;
    const int c4   = rr & 3;      // key-parity chunk (mod 4)
    const int pr   = rr >> 2;     // pair index 0..7

    __shared__ __align__(128) unsigned char smem[65536];  // 2 x (K 16K + V 16K)

    const size_t bbase = (size_t)b * S_ * H_;
    const unsigned char* Kb = (const unsigned char*)(Kg + bbase);
    const unsigned char* Vb = (const unsigned char*)(Vtg + (size_t)b*H_*S_);
    const int swzq = (c31 & 7) << 4;

    int cur = 0;
    for (int ph = 0; ph < 2; ++ph) {
        const int qt   = ph ? (15 - pr) : pr;
        const int q0   = qt * 256;
        const int qw0  = q0 + w*32;
        const int qrow = qw0 + c31;
        const int nkt  = 4*(qt+1);

        short8 qf[8];
        {
            const unsigned short* qp = Qg + bbase + (size_t)qrow * H_;
            #pragma unroll
            for (int ks=0; ks<8; ++ks)
                qf[ks] = *(const short8*)(qp + ks*16 + hi*8);
        }

        f32x16 oacc[4];
        #pragma unroll
        for (int ht=0; ht<4; ++ht)
            #pragma unroll
            for (int r=0; r<16; ++r) oacc[ht][r] = 0.f;
        float mrun = -1e30f, lrun = 0.f;

        stage_tile(smem + cur*32768, Kb, Vb, c4, w, l);
        __syncthreads();

        for (int kt = c4; kt < nkt; kt += 4) {
            const bool pre = (kt+4 < nkt);
            if (pre) stage_tile(smem + (cur^1)*32768, Kb, Vb, kt+4, w, l);

            if (kt*64 <= qw0 + 31) {
                const unsigned char* sK = smem + cur*32768;
                const unsigned char* sV = sK + 16384;

                f32x16 sacc[2];
                #pragma unroll
                for (int st=0; st<2; ++st)
                    #pragma unroll
                    for (int r=0; r<16; ++r) sacc[st][r] = 0.f;
                #pragma unroll
                for (int st=0; st<2; ++st) {
                    int krow = st*32 + c31;
                    #pragma unroll
                    for (int ks=0; ks<8; ++ks) {
                        short8 kf = *(const short8*)(sK + krow*256 + ((ks*32 + hi*16) ^ swzq));
                        sacc[st] = __builtin_amdgcn_mfma_f32_32x32x16_bf16(kf, qf[ks], sacc[st], 0,0,0);
                    }
                }

                if (kt*64 + 63 > qw0) {
                    #pragma unroll
                    for (int st=0; st<2; ++st)
                        #pragma unroll
                        for (int r=0; r<16; ++r) {
                            int key = kt*64 + st*32 + (r&3) + 8*(r>>2) + 4*hi;
                            if (key > qrow) sacc[st][r] = -1e30f;
                        }
                }

                float pmax = -1e30f;
                #pragma unroll
                for (int st=0; st<2; ++st)
                    #pragma unroll
                    for (int r=0; r<16; ++r) pmax = fmaxf(pmax, sacc[st][r]);
                pmax = fmaxf(pmax, __shfl_xor(pmax, 32, 64));

                if (!__all(pmax - mrun <= 8.0f)) {
                    float mnew = fmaxf(mrun, pmax);
                    float alpha = __expf(mrun - mnew);
                    #pragma unroll
                    for (int ht=0; ht<4; ++ht)
                        #pragma unroll
                        for (int r=0; r<16; ++r) oacc[ht][r] *= alpha;
                    lrun *= alpha;
                    mrun = mnew;
                }

                float p[2][16];
                float psum = 0.f;
                #pragma unroll
                for (int st=0; st<2; ++st)
                    #pragma unroll
                    for (int r=0; r<16; ++r) {
                        float e = __expf(sacc[st][r] - mrun);
                        p[st][r] = e;
                        psum += e;
                    }
                psum += __shfl_xor(psum, 32, 64);
                lrun += psum;

                short8 pf[4];
                #pragma unroll
                for (int st=0; st<2; ++st) {
                    uint32_t A0 = cvt_pk_bf16(p[st][0],  p[st][1]);
                    uint32_t A1 = cvt_pk_bf16(p[st][2],  p[st][3]);
                    uint32_t B0 = cvt_pk_bf16(p[st][4],  p[st][5]);
                    uint32_t B1 = cvt_pk_bf16(p[st][6],  p[st][7]);
                    uint32_t C0 = cvt_pk_bf16(p[st][8],  p[st][9]);
                    uint32_t C1 = cvt_pk_bf16(p[st][10], p[st][11]);
                    uint32_t D0 = cvt_pk_bf16(p[st][12], p[st][13]);
                    uint32_t D1 = cvt_pk_bf16(p[st][14], p[st][15]);
                    {
                        uint32_t x0 = hi ? A0 : B0;
                        uint32_t x1 = hi ? A1 : B1;
                        uint32_t y0 = (uint32_t)__shfl_xor((int)x0, 32, 64);
                        uint32_t y1 = (uint32_t)__shfl_xor((int)x1, 32, 64);
                        union { uint32_t u[4]; short8 s; } uu;
                        uu.u[0] = hi ? y0 : A0;
                        uu.u[1] = hi ? y1 : A1;
                        uu.u[2] = hi ? B0 : y0;
                        uu.u[3] = hi ? B1 : y1;
                        pf[st*2] = uu.s;
                    }
                    {
                        uint32_t x0 = hi ? C0 : D0;
                        uint32_t x1 = hi ? C1 : D1;
                        uint32_t y0 = (uint32_t)__shfl_xor((int)x0, 32, 64);
                        uint32_t y1 = (uint32_t)__shfl_xor((int)x1, 32, 64);
                        union { uint32_t u[4]; short8 s; } uu;
                        uu.u[0] = hi ? y0 : C0;
                        uu.u[1] = hi ? y1 : C1;
                        uu.u[2] = hi ? D0 : y0;
                        uu.u[3] = hi ? D1 : y1;
                        pf[st*2+1] = uu.s;
                    }
                }

                #pragma unroll
                for (int sl=0; sl<4; ++sl) {
                    #pragma unroll
                    for (int ht=0; ht<4; ++ht) {
                        int h = ht*32 + c31;
                        short8 vf = *(const short8*)(sV + h*128 + ((sl*32 + hi*16) ^ swzq));
                        oacc[ht] = __builtin_amdgcn_mfma_f32_32x32x16_bf16(vf, pf[sl], oacc[ht], 0,0,0);
                    }
                }
            }

            __syncthreads();   // drains global_load_lds (vmcnt) + phase separation
            if (pre) cur ^= 1;
        }

        // write partials for (qt, chunk c4)
        float* Prow = Pp + (size_t)c4*((size_t)M_*H_) + bbase + (size_t)qrow*H_;
        #pragma unroll
        for (int ht=0; ht<4; ++ht)
            #pragma unroll
            for (int k=0; k<4; ++k) {
                float4 o;
                o.x = oacc[ht][4*k+0];
                o.y = oacc[ht][4*k+1];
                o.z = oacc[ht][4*k+2];
                o.w = oacc[ht][4*k+3];
                *(float4*)(Prow + ht*32 + 8*k + 4*hi) = o;
            }
        if (hi == 0) {
            float2 ml2; ml2.x = mrun; ml2.y = lrun;
            *(float2*)(Ml + ((size_t)c4*M_ + (size_t)b*S_ + qrow)*2) = ml2;
        }
    }
}

// ---------------- merge: renormalize 4 partials ----------------
__global__ __launch_bounds__(256)
void attn_merge(const float* __restrict__ Pp, const float* __restrict__ Ml,
                float* __restrict__ Out)
{
    int gid = blockIdx.x*256 + threadIdx.x;
    int q  = gid >> 5;
    int h4 = gid & 31;

    float m0 = Ml[((size_t)0*M_ + q)*2], l0 = Ml[((size_t)0*M_ + q)*2 + 1];
    float m1 = Ml[((size_t)1*M_ + q)*2], l1 = Ml[((size_t)1*M_ + q)*2 + 1];
    float m2 = Ml[((size_t)2*M_ + q)*2], l2 = Ml[((size_t)2*M_ + q)*2 + 1];
    float m3 = Ml[((size_t)3*M_ + q)*2], l3 = Ml[((size_t)3*M_ + q)*2 + 1];

    float M = fmaxf(fmaxf(m0, m1), fmaxf(m2, m3));
    float w0 = __expf(m0 - M), w1 = __expf(m1 - M);
    float w2 = __expf(m2 - M), w3 = __expf(m3 - M);
    float L = w0*l0 + w1*l1 + w2*l2 + w3*l3;

    float4 p0 = *(const float4*)(Pp + (size_t)0*((size_t)M_*H_) + (size_t)q*H_ + h4*4);
    float4 p1 = *(const float4*)(Pp + (size_t)1*((size_t)M_*H_) + (size_t)q*H_ + h4*4);
    float4 p2 = *(const float4*)(Pp + (size_t)2*((size_t)M_*H_) + (size_t)q*H_ + h4*4);
    float4 p3 = *(const float4*)(Pp + (size_t)3*((size_t)M_*H_) + (size_t)q*H_ + h4*4);
    float inv = 1.0f / L;
    float4 o;
    o.x = (w0*p0.x + w1*p1.x + w2*p2.x + w3*p3.x) * inv;
    o.y = (w0*p0.y + w1*p1.y + w2*p2.y + w3*p3.y) * inv;
    o.z = (w0*p0.z + w1*p1.z + w2*p2.z + w3*p3.z) * inv;
    o.w = (w0*p0.w + w1*p1.w + w2*p2.w + w3*p3.w) * inv;
    *(float4*)(Out + (size_t)q*H_ + h4*4) = o;
}

// ---------------- fallback (v3 single-pass attn) if ws too small ----------------
__global__ __launch_bounds__(128, 1)
void attn_fb(const unsigned short* __restrict__ Qg,
             const unsigned short* __restrict__ Kg,
             const unsigned short* __restrict__ Vtg,
             float* __restrict__ Out)
{
    const int t   = threadIdx.x;
    const int w   = t >> 6;
    const int l   = t & 63;
    const int hi  = l >> 5;
    const int c31 = l & 31;
    const int qt  = (S_/64 - 1) - blockIdx.x;
    const int b   = blockIdx.y;
    const int q0  = qt * 64;
    const int qrow = q0 + w*32 + c31;

    __shared__ __align__(128) unsigned char sK[16384];
    __shared__ __align__(128) unsigned char sV[16384];

    const size_t bbase = (size_t)b * S_ * H_;

    short8 qf[8];
    {
        const unsigned short* qp = Qg + bbase + (size_t)qrow * H_;
        #pragma unroll
        for (int ks=0; ks<8; ++ks)
            qf[ks] = *(const short8*)(qp + ks*16 + hi*8);
    }

    f32x16 oacc[4];
    #pragma unroll
    for (int ht=0; ht<4; ++ht)
        #pragma unroll
        for (int r=0; r<16; ++r) oacc[ht][r] = 0.f;
    float mrun = -1e30f, lrun = 0.f;

    const unsigned char* Kb = (const unsigned char*)(Kg + bbase);
    const unsigned char* Vb = (const unsigned char*)(Vtg + (size_t)b*H_*S_);
    const int swzq = (c31 & 7) << 4;

    for (int kt=0; kt<=qt; ++kt) {
        __syncthreads();
        #pragma unroll
        for (int i=0;i<8;++i) {
            int c = i*128 + t;
            int row = c >> 4, cb = (c & 15) * 16;
            *(uint4*)(sK + row*256 + (cb ^ ((row&7)<<4))) =
                *(const uint4*)(Kb + (size_t)(kt*64 + row)*256 + cb);
        }
        #pragma unroll
        for (int i=0;i<8;++i) {
            int c = i*128 + t;
            int h = c >> 3, cb = (c & 7) * 16;
            *(uint4*)(sV + h*128 + (cb ^ ((h&7)<<4))) =
                *(const uint4*)(Vb + (size_t)h*(S_*2) + kt*128 + cb);
        }
        __syncthreads();

        f32x16 sacc[2];
        #pragma unroll
        for (int st=0; st<2; ++st)
            #pragma unroll
            for (int r=0; r<16; ++r) sacc[st][r] = 0.f;
        #pragma unroll
        for (int st=0; st<2; ++st) {
            int krow = st*32 + c31;
            #pragma unroll
            for (int ks=0; ks<8; ++ks) {
                short8 kf = *(const short8*)(sK + krow*256 + ((ks*32 + hi*16) ^ swzq));
                sacc[st] = __builtin_amdgcn_mfma_f32_32x32x16_bf16(kf, qf[ks], sacc[st], 0,0,0);
            }
        }

        if (kt == qt) {
            #pragma unroll
            for (int st=0; st<2; ++st)
                #pragma unroll
                for (int r=0; r<16; ++r) {
                    int key = q0 + st*32 + (r&3) + 8*(r>>2) + 4*hi;
                    if (key > qrow) sacc[st][r] = -1e30f;
                }
        }

        float pmax = -1e30f;
        #pragma unroll
        for (int st=0; st<2; ++st)
            #pragma unroll
            for (int r=0; r<16; ++r) pmax = fmaxf(pmax, sacc[st][r]);
        pmax = fmaxf(pmax, __shfl_xor(pmax, 32, 64));

        if (!__all(pmax - mrun <= 8.0f)) {
            float mnew = fmaxf(mrun, pmax);
            float alpha = __expf(mrun - mnew);
            #pragma unroll
            for (int ht=0; ht<4; ++ht)
                #pragma unroll
                for (int r=0; r<16; ++r) oacc[ht][r] *= alpha;
            lrun *= alpha;
            mrun = mnew;
        }

        float p[2][16];
        float psum = 0.f;
        #pragma unroll
        for (int st=0; st<2; ++st)
            #pragma unroll
            for (int r=0; r<16; ++r) {
                float e = __expf(sacc[st][r] - mrun);
                p[st][r] = e;
                psum += e;
            }
        psum += __shfl_xor(psum, 32, 64);
        lrun += psum;

        short8 pf[4];
        #pragma unroll
        for (int st=0; st<2; ++st) {
            uint32_t A0 = cvt_pk_bf16(p[st][0],  p[st][1]);
            uint32_t A1 = cvt_pk_bf16(p[st][2],  p[st][3]);
            uint32_t B0 = cvt_pk_bf16(p[st][4],  p[st][5]);
            uint32_t B1 = cvt_pk_bf16(p[st][6],  p[st][7]);
            uint32_t C0 = cvt_pk_bf16(p[st][8],  p[st][9]);
            uint32_t C1 = cvt_pk_bf16(p[st][10], p[st][11]);
            uint32_t D0 = cvt_pk_bf16(p[st][12], p[st][13]);
            uint32_t D1 = cvt_pk_bf16(p[st][14], p[st][15]);
            {
                uint32_t x0 = hi ? A0 : B0;
                uint32_t x1 = hi ? A1 : B1;
                uint32_t y0 = (uint32_t)__shfl_xor((int)x0, 32, 64);
                uint32_t y1 = (uint32_t)__shfl_xor((int)x1, 32, 64);
                union { uint32_t u[4]; short8 s; } uu;
                uu.u[0] = hi ? y0 : A0;
                uu.u[1] = hi ? y1 : A1;
                uu.u[2] = hi ? B0 : y0;
                uu.u[3] = hi ? B1 : y1;
                pf[st*2] = uu.s;
            }
            {
                uint32_t x0 = hi ? C0 : D0;
                uint32_t x1 = hi ? C1 : D1;
                uint32_t y0 = (uint32_t)__shfl_xor((int)x0, 32, 64);
                uint32_t y1 = (uint32_t)__shfl_xor((int)x1, 32, 64);
                union { uint32_t u[4]; short8 s; } uu;
                uu.u[0] = hi ? y0 : C0;
                uu.u[1] = hi ? y1 : C1;
                uu.u[2] = hi ? D0 : y0;
                uu.u[3] = hi ? D1 : y1;
                pf[st*2+1] = uu.s;
            }
        }

        #pragma unroll
        for (int sl=0; sl<4; ++sl) {
            #pragma unroll
            for (int ht=0; ht<4; ++ht) {
                int h = ht*32 + c31;
                short8 vf = *(const short8*)(sV + h*128 + ((sl*32 + hi*16) ^ swzq));
                oacc[ht] = __builtin_amdgcn_mfma_f32_32x32x16_bf16(vf, pf[sl], oacc[ht], 0,0,0);
            }
        }
    }

    float linv = 1.0f / lrun;
    float* Op = Out + bbase + (size_t)qrow * H_;
    #pragma unroll
    for (int ht=0; ht<4; ++ht)
        #pragma unroll
        for (int k=0; k<4; ++k) {
            float4 o;
            o.x = oacc[ht][4*k+0] * linv;
            o.y = oacc[ht][4*k+1] * linv;
            o.z = oacc[ht][4*k+2] * linv;
            o.w = oacc[ht][4*k+3] * linv;
            *(float4*)(Op + ht*32 + 8*k + 4*hi) = o;
        }
}

extern "C" void kernel_launch(void* const* d_in, const int* in_sizes, int n_in,
                              void* d_out, int out_size, void* d_ws, size_t ws_size,
                              hipStream_t stream) {
    const float* x  = (const float*)d_in[0];
    const float* Wq = (const float*)d_in[1];
    const float* Wk = (const float*)d_in[2];
    const float* Wv = (const float*)d_in[3];

    unsigned char* ws = (unsigned char*)d_ws;
    unsigned short* Wt  = (unsigned short*)ws;                          // 768 KB @ 0
    unsigned short* Qg  = (unsigned short*)(ws + 1048576u);             // 8 MB
    unsigned short* Kg  = (unsigned short*)(ws + 9437184u);             // 8 MB
    unsigned short* Vtg = (unsigned short*)(ws + 17825792u);            // 8 MB
    float* Pp = (float*)(ws + 26214400u);                               // 64 MB (4 chunks)
    float* Ml = (float*)(ws + 93323264u);                               // 1 MB
    const size_t NEED = 94371840u;

    prep_w_kernel<<<192, 256, 0, stream>>>(Wq, Wk, Wv, Wt);
    proj_kernel<<<256, 512, 0, stream>>>(x, Wt, Qg, Kg, Vtg);

    if (ws_size >= NEED) {
        attn_p1<<<256, 512, 0, stream>>>(Qg, Kg, Vtg, Pp, Ml);
        attn_merge<<<4096, 256, 0, stream>>>(Pp, Ml, (float*)d_out);
    } else {
        dim3 ga(S_/64, B_);
        attn_fb<<<ga, 128, 0, stream>>>(Qg, Kg, Vtg, (float*)d_out);
    }
}